// Round 1
// baseline (1161.880 us; speedup 1.0000x reference)
//
#include <hip/hip_runtime.h>

static constexpr float SLOPE = 0.01f;   // leaky_relu negative_slope
static constexpr float EPSN  = 1e-12f;  // F.normalize eps

// h[row, col] = leaky_relu(sum_k x[row,k] * W[k,col] + b[col]), hid = 64
__global__ void gemm_lrelu_k(const float* __restrict__ x, const float* __restrict__ W,
                             const float* __restrict__ b, float* __restrict__ h,
                             int n, int in_dim) {
  const int col = threadIdx.x & 63;
  const int row = blockIdx.x * (blockDim.x >> 6) + (threadIdx.x >> 6);
  if (row >= n) return;
  const float* xr = x + (size_t)row * in_dim;
  float acc = b[col];
  int k = 0;
  if ((in_dim & 3) == 0) {  // row base stays 16B-aligned (in_dim=500 -> 2000B rows)
    for (; k < in_dim; k += 4) {
      const float4 xv = *reinterpret_cast<const float4*>(xr + k);
      acc = fmaf(xv.x, W[(size_t)(k + 0) * 64 + col], acc);
      acc = fmaf(xv.y, W[(size_t)(k + 1) * 64 + col], acc);
      acc = fmaf(xv.z, W[(size_t)(k + 2) * 64 + col], acc);
      acc = fmaf(xv.w, W[(size_t)(k + 3) * 64 + col], acc);
    }
  }
  for (; k < in_dim; ++k) acc = fmaf(xr[k], W[(size_t)k * 64 + col], acc);
  h[(size_t)row * 64 + col] = acc > 0.0f ? acc : SLOPE * acc;
}

// L2-normalize each 8-elem capsule chunk. Layout: idx = row*64 + (cap*8 + dim).
// Requires total % 64 == 0 (true: total = n*64) so shfl groups stay intact.
__global__ void capsnorm_k(const float* __restrict__ in, float* __restrict__ out, int total) {
  const int idx = blockIdx.x * blockDim.x + threadIdx.x;
  if (idx >= total) return;
  const float v = in[idx];
  float s = v * v;
  s += __shfl_xor(s, 1);
  s += __shfl_xor(s, 2);
  s += __shfl_xor(s, 4);
  const float nr = fmaxf(sqrtf(s), EPSN);
  out[idx] = v / nr;
}

__global__ void copy4_k(const float4* __restrict__ in, float4* __restrict__ out, int total4) {
  const int idx = blockIdx.x * blockDim.x + threadIdx.x;
  if (idx < total4) out[idx] = in[idx];
}

__global__ void lrelu_k(const float* __restrict__ in, float* __restrict__ out, int total) {
  const int idx = blockIdx.x * blockDim.x + threadIdx.x;
  if (idx >= total) return;
  const float v = in[idx];
  out[idx] = v > 0.0f ? v : SLOPE * v;
}

// One wave per edge. lane = cap*8 + dim (hid=64, K=8, dd=8).
// p_cap = dot(z_cap, u[trg]_cap); softmax over caps; atomicAdd z*w into unew[trg].
__global__ void edge_route_k(const int* __restrict__ src, const int* __restrict__ trg,
                             const float* __restrict__ xn, const float* __restrict__ u,
                             float* __restrict__ unew, int m) {
  const int wave = (int)((blockIdx.x * (size_t)blockDim.x + threadIdx.x) >> 6);
  const int lane = threadIdx.x & 63;
  if (wave >= m) return;
  const int s = src[wave];
  const int t = trg[wave];
  const float z  = xn[(size_t)s * 64 + lane];
  const float uv = u[(size_t)t * 64 + lane];
  // per-capsule agreement score (8-lane reduce)
  float p = z * uv;
  p += __shfl_xor(p, 1);
  p += __shfl_xor(p, 2);
  p += __shfl_xor(p, 4);
  // softmax across the 8 capsules (lanes differing in bits 3..5), tau = 1
  float mx = p;
  mx = fmaxf(mx, __shfl_xor(mx, 8));
  mx = fmaxf(mx, __shfl_xor(mx, 16));
  mx = fmaxf(mx, __shfl_xor(mx, 32));
  const float e = __expf(p - mx);
  float sum = e;
  sum += __shfl_xor(sum, 8);
  sum += __shfl_xor(sum, 16);
  sum += __shfl_xor(sum, 32);
  const float w = e / sum;
  atomicAdd(&unew[(size_t)t * 64 + lane], z * w);
}

extern "C" void kernel_launch(void* const* d_in, const int* in_sizes, int n_in,
                              void* d_out, int out_size, void* d_ws, size_t ws_size,
                              hipStream_t stream) {
  const float* x       = (const float*)d_in[0];
  const int*   src_trg = (const int*)d_in[1];
  const float* W       = (const float*)d_in[2];
  const float* b       = (const float*)d_in[3];
  float* out = (float*)d_out;

  const int hid    = in_sizes[3];          // 64
  const int in_dim = in_sizes[2] / hid;    // 500
  const int n      = in_sizes[0] / in_dim; // 50000
  const int m      = in_sizes[1] / 2;      // 500000
  const int* src = src_trg;
  const int* trg = src_trg + m;

  const size_t n64 = (size_t)n * hid;      // 3.2M floats
  float* ws = (float*)d_ws;
  float* xn = ws;                          // capsnorm'd layer input ("x" in rout)
  float* ua = ws + n64;                    // routing ping
  float* ub = ws + 2 * n64;                // routing pong
  float* h  = out;                         // d_out doubles as the feature buffer

  const int total  = (int)n64;
  const int nb     = (total + 255) / 256;
  const int nb4    = (total / 4 + 255) / 256;
  const int rows_per_block = 256 / 64;

  // 1) h = leaky_relu(x @ W + b)
  gemm_lrelu_k<<<(n + rows_per_block - 1) / rows_per_block, 256, 0, stream>>>(
      x, W, b, h, n, in_dim);

  const int edge_blocks = (m + 3) / 4;     // 4 waves (edges) per 256-thread block

  for (int layer = 0; layer < 2; ++layer) {
    // xn = capsnorm(h)
    capsnorm_k<<<nb, 256, 0, stream>>>(h, xn, total);
    const float* u = xn;
    float* ucur = nullptr;
    for (int t = 0; t < 3; ++t) {
      float* unew = (t & 1) ? ub : ua;
      // unew = xn  (the "+ x" term of segment_sum(msg) + x)
      copy4_k<<<nb4, 256, 0, stream>>>((const float4*)xn, (float4*)unew, total / 4);
      // unew += segment_sum(z * softmax(p), trg)
      edge_route_k<<<edge_blocks, 256, 0, stream>>>(src, trg, xn, u, unew, m);
      // unew = capsnorm(unew)   (in-place is safe: element-wise + register shfl)
      capsnorm_k<<<nb, 256, 0, stream>>>(unew, unew, total);
      u = unew;
      ucur = unew;
    }
    // h = leaky_relu(u)  (last layer writes the final output in d_out)
    lrelu_k<<<nb, 256, 0, stream>>>(ucur, h, total);
  }
}

// Round 2
// 890.115 us; speedup vs baseline: 1.3053x; 1.3053x over previous
//
#include <hip/hip_runtime.h>

static constexpr float SLOPE = 0.01f;   // leaky_relu negative_slope
static constexpr float EPSN  = 1e-12f;  // F.normalize eps

#define BM 64     // rows per block
#define BK 100    // k-tile (in_dim = 500 = 5 * 100, tail-free)

// Fused: xn = capsnorm(leaky_relu(x @ W + b)).  hid = 64, K = 8 capsules of 8.
// Block: 256 threads -> 64 rows x 64 cols, per-thread 4x4 register tile.
__global__ __launch_bounds__(256) void gemm_lrelu_capsnorm_k(
    const float* __restrict__ x, const float* __restrict__ W,
    const float* __restrict__ b, float* __restrict__ xn, int n, int in_dim) {
  __shared__ float xs[BK][BM];   // transposed x tile: xs[k][row]
  __shared__ float ws[BK][64];   // W tile: ws[k][col]

  const int tid  = threadIdx.x;
  const int row0 = blockIdx.x * BM;
  const int colg = (tid & 15) * 4;   // 16 col-groups of 4
  const int rowg = (tid >> 4) * 4;   // 16 row-groups of 4

  float acc[4][4];
#pragma unroll
  for (int i = 0; i < 4; ++i)
#pragma unroll
    for (int j = 0; j < 4; ++j) acc[i][j] = 0.0f;

  for (int k0 = 0; k0 < in_dim; k0 += BK) {
    // stage x tile (transposed). BM*BK/4 = 1600 float4 loads, 16B-aligned:
    // row base = grow*2000B, k offset = 400B * iter -> both 16B multiples.
    for (int idx = tid; idx < BM * (BK / 4); idx += 256) {
      const int r  = idx / (BK / 4);
      const int kq = idx % (BK / 4);
      float4 v = make_float4(0.f, 0.f, 0.f, 0.f);
      const int grow = row0 + r;
      if (grow < n)
        v = *reinterpret_cast<const float4*>(x + (size_t)grow * in_dim + k0 + kq * 4);
      xs[kq * 4 + 0][r] = v.x;
      xs[kq * 4 + 1][r] = v.y;
      xs[kq * 4 + 2][r] = v.z;
      xs[kq * 4 + 3][r] = v.w;
    }
    // stage W tile: contiguous BK*64 floats starting at W + k0*64
    for (int idx = tid; idx < BK * 64 / 4; idx += 256) {
      *reinterpret_cast<float4*>(&ws[0][0] + idx * 4) =
          *reinterpret_cast<const float4*>(W + (size_t)k0 * 64 + idx * 4);
    }
    __syncthreads();

#pragma unroll 10
    for (int k = 0; k < BK; ++k) {
      const float4 a  = *reinterpret_cast<const float4*>(&xs[k][rowg]);
      const float4 bb = *reinterpret_cast<const float4*>(&ws[k][colg]);
      acc[0][0] = fmaf(a.x, bb.x, acc[0][0]);
      acc[0][1] = fmaf(a.x, bb.y, acc[0][1]);
      acc[0][2] = fmaf(a.x, bb.z, acc[0][2]);
      acc[0][3] = fmaf(a.x, bb.w, acc[0][3]);
      acc[1][0] = fmaf(a.y, bb.x, acc[1][0]);
      acc[1][1] = fmaf(a.y, bb.y, acc[1][1]);
      acc[1][2] = fmaf(a.y, bb.z, acc[1][2]);
      acc[1][3] = fmaf(a.y, bb.w, acc[1][3]);
      acc[2][0] = fmaf(a.z, bb.x, acc[2][0]);
      acc[2][1] = fmaf(a.z, bb.y, acc[2][1]);
      acc[2][2] = fmaf(a.z, bb.z, acc[2][2]);
      acc[2][3] = fmaf(a.z, bb.w, acc[2][3]);
      acc[3][0] = fmaf(a.w, bb.x, acc[3][0]);
      acc[3][1] = fmaf(a.w, bb.y, acc[3][1]);
      acc[3][2] = fmaf(a.w, bb.z, acc[3][2]);
      acc[3][3] = fmaf(a.w, bb.w, acc[3][3]);
    }
    __syncthreads();
  }

  // Epilogue: bias + leaky_relu + capsnorm, all in registers.
  // Thread owns cols [colg, colg+4); capsule = 8 cols -> partner thread is tid^1
  // (adjacent lane, same wave). No early exits before the shfl.
  const float4 bv = *reinterpret_cast<const float4*>(b + colg);
#pragma unroll
  for (int i = 0; i < 4; ++i) {
    float v0 = acc[i][0] + bv.x;
    float v1 = acc[i][1] + bv.y;
    float v2 = acc[i][2] + bv.z;
    float v3 = acc[i][3] + bv.w;
    v0 = v0 > 0.f ? v0 : SLOPE * v0;
    v1 = v1 > 0.f ? v1 : SLOPE * v1;
    v2 = v2 > 0.f ? v2 : SLOPE * v2;
    v3 = v3 > 0.f ? v3 : SLOPE * v3;
    float s = v0 * v0 + v1 * v1 + v2 * v2 + v3 * v3;
    s += __shfl_xor(s, 1);                   // full 8-col capsule sum
    const float inv = 1.0f / fmaxf(sqrtf(s), EPSN);
    const int grow = row0 + rowg + i;
    if (grow < n) {
      float4 o = make_float4(v0 * inv, v1 * inv, v2 * inv, v3 * inv);
      *reinterpret_cast<float4*>(xn + (size_t)grow * 64 + colg) = o;
    }
  }
}

// L2-normalize each 8-elem capsule chunk. idx = row*64 + (cap*8 + dim).
__global__ __launch_bounds__(256) void capsnorm_k(const float* __restrict__ in,
                                                  float* __restrict__ out, int total) {
  const int idx = blockIdx.x * blockDim.x + threadIdx.x;
  if (idx >= total) return;
  const float v = in[idx];
  float s = v * v;
  s += __shfl_xor(s, 1);
  s += __shfl_xor(s, 2);
  s += __shfl_xor(s, 4);
  const float nr = fmaxf(sqrtf(s), EPSN);
  out[idx] = v / nr;
}

// xn_next = capsnorm(leaky_relu(u))  (layer boundary, fused)
__global__ __launch_bounds__(256) void capsnorm_lrelu_k(const float* __restrict__ in,
                                                        float* __restrict__ out, int total) {
  const int idx = blockIdx.x * blockDim.x + threadIdx.x;
  if (idx >= total) return;
  float v = in[idx];
  v = v > 0.f ? v : SLOPE * v;
  float s = v * v;
  s += __shfl_xor(s, 1);
  s += __shfl_xor(s, 2);
  s += __shfl_xor(s, 4);
  const float nr = fmaxf(sqrtf(s), EPSN);
  out[idx] = v / nr;
}

__global__ __launch_bounds__(256) void copy4_k(const float4* __restrict__ in,
                                               float4* __restrict__ out, int total4) {
  const int idx = blockIdx.x * blockDim.x + threadIdx.x;
  if (idx < total4) out[idx] = in[idx];
}

__global__ __launch_bounds__(256) void lrelu_k(const float* __restrict__ in,
                                               float* __restrict__ out, int total) {
  const int idx = blockIdx.x * blockDim.x + threadIdx.x;
  if (idx >= total) return;
  const float v = in[idx];
  out[idx] = v > 0.f ? v : SLOPE * v;
}

// One wave per edge. lane = cap*8 + dim (hid=64, K=8, dd=8).
__global__ __launch_bounds__(256) void edge_route_k(
    const int* __restrict__ src, const int* __restrict__ trg,
    const float* __restrict__ xn, const float* __restrict__ u,
    float* __restrict__ unew, int m) {
  const int wave = (int)((blockIdx.x * (size_t)blockDim.x + threadIdx.x) >> 6);
  const int lane = threadIdx.x & 63;
  if (wave >= m) return;
  const int s = src[wave];
  const int t = trg[wave];
  const float z  = xn[(size_t)s * 64 + lane];
  const float uv = u[(size_t)t * 64 + lane];
  float p = z * uv;
  p += __shfl_xor(p, 1);
  p += __shfl_xor(p, 2);
  p += __shfl_xor(p, 4);
  float mx = p;
  mx = fmaxf(mx, __shfl_xor(mx, 8));
  mx = fmaxf(mx, __shfl_xor(mx, 16));
  mx = fmaxf(mx, __shfl_xor(mx, 32));
  const float e = __expf(p - mx);
  float sum = e;
  sum += __shfl_xor(sum, 8);
  sum += __shfl_xor(sum, 16);
  sum += __shfl_xor(sum, 32);
  const float w = e / sum;
  atomicAdd(&unew[(size_t)t * 64 + lane], z * w);
}

extern "C" void kernel_launch(void* const* d_in, const int* in_sizes, int n_in,
                              void* d_out, int out_size, void* d_ws, size_t ws_size,
                              hipStream_t stream) {
  const float* x       = (const float*)d_in[0];
  const int*   src_trg = (const int*)d_in[1];
  const float* W       = (const float*)d_in[2];
  const float* b       = (const float*)d_in[3];
  float* out = (float*)d_out;

  const int hid    = in_sizes[3];          // 64
  const int in_dim = in_sizes[2] / hid;    // 500
  const int n      = in_sizes[0] / in_dim; // 50000
  const int m      = in_sizes[1] / 2;      // 500000
  const int* src = src_trg;
  const int* trg = src_trg + m;

  const size_t n64 = (size_t)n * hid;      // 3.2M floats
  float* ws = (float*)d_ws;
  float* xn = ws;                          // capsnorm'd layer input ("x" in rout)
  float* ua = ws + n64;                    // routing ping
  float* ub = ws + 2 * n64;                // routing pong

  const int total = (int)n64;
  const int nb    = (total + 255) / 256;
  const int nb4   = (total / 4 + 255) / 256;

  // 1) xn = capsnorm(leaky_relu(x @ W + b))   (fused GEMM)
  gemm_lrelu_capsnorm_k<<<(n + BM - 1) / BM, 256, 0, stream>>>(x, W, b, xn, n, in_dim);

  const int edge_blocks = (m + 3) / 4;     // 4 waves (edges) per 256-thread block

  float* ucur = nullptr;
  for (int layer = 0; layer < 2; ++layer) {
    if (layer > 0) {
      // xn = capsnorm(leaky_relu(u_prev))  (fused layer boundary)
      capsnorm_lrelu_k<<<nb, 256, 0, stream>>>(ucur, xn, total);
    }
    const float* u = xn;
    for (int t = 0; t < 3; ++t) {
      float* unew = (t & 1) ? ub : ua;
      // unew = xn  (the "+ x" term of segment_sum(msg) + x)
      copy4_k<<<nb4, 256, 0, stream>>>((const float4*)xn, (float4*)unew, total / 4);
      // unew += segment_sum(z * softmax(p), trg)
      edge_route_k<<<edge_blocks, 256, 0, stream>>>(src, trg, xn, u, unew, m);
      // unew = capsnorm(unew)  (in-place: elementwise + register shfl)
      capsnorm_k<<<nb, 256, 0, stream>>>(unew, unew, total);
      u = unew;
      ucur = unew;
    }
  }
  // final: out = leaky_relu(u_final)
  lrelu_k<<<nb, 256, 0, stream>>>(ucur, out, total);
}

// Round 3
// 545.773 us; speedup vs baseline: 2.1289x; 1.6309x over previous
//
#include <hip/hip_runtime.h>

static constexpr float SLOPE = 0.01f;   // leaky_relu negative_slope
static constexpr float EPSN  = 1e-12f;  // F.normalize eps

#define BM 64     // rows per block
#define BK 100    // k-tile (in_dim = 500 = 5 * 100, tail-free)

// ---------------------------------------------------------------------------
// Fused: xn = capsnorm(leaky_relu(x @ W + b)).  hid = 64, K = 8 capsules of 8.
// 256 threads -> 64 rows x 64 cols, per-thread 4x4 register tile.
// Staging decomposition r=idx&63, kq=idx>>6: a wave's 64 lanes write 64
// different rows -> banks r%32, 2-way aliasing (free). k-loop reads are
// broadcast/2-way -> conflict-free.
// ---------------------------------------------------------------------------
__global__ __launch_bounds__(256) void gemm_lrelu_capsnorm_k(
    const float* __restrict__ x, const float* __restrict__ W,
    const float* __restrict__ b, float* __restrict__ xn, int n, int in_dim) {
  __shared__ float xs[BK][BM];   // transposed x tile: xs[k][row]
  __shared__ float ws[BK][64];   // W tile: ws[k][col]

  const int tid  = threadIdx.x;
  const int row0 = blockIdx.x * BM;
  const int colg = (tid & 15) * 4;   // 16 col-groups of 4
  const int rowg = (tid >> 4) * 4;   // 16 row-groups of 4

  float acc[4][4];
#pragma unroll
  for (int i = 0; i < 4; ++i)
#pragma unroll
    for (int j = 0; j < 4; ++j) acc[i][j] = 0.0f;

  for (int k0 = 0; k0 < in_dim; k0 += BK) {
    // stage x tile (transposed), conflict-free writes
    for (int idx = tid; idx < BM * (BK / 4); idx += 256) {
      const int r  = idx & 63;        // row within tile
      const int kq = idx >> 6;        // float4 chunk within k-tile (0..24)
      float4 v = make_float4(0.f, 0.f, 0.f, 0.f);
      const int grow = row0 + r;
      if (grow < n)
        v = *reinterpret_cast<const float4*>(x + (size_t)grow * in_dim + k0 + kq * 4);
      xs[kq * 4 + 0][r] = v.x;
      xs[kq * 4 + 1][r] = v.y;
      xs[kq * 4 + 2][r] = v.z;
      xs[kq * 4 + 3][r] = v.w;
    }
    // stage W tile: contiguous BK*64 floats
    for (int idx = tid; idx < BK * 64 / 4; idx += 256) {
      *reinterpret_cast<float4*>(&ws[0][0] + idx * 4) =
          *reinterpret_cast<const float4*>(W + (size_t)k0 * 64 + idx * 4);
    }
    __syncthreads();

#pragma unroll 10
    for (int k = 0; k < BK; ++k) {
      const float4 a  = *reinterpret_cast<const float4*>(&xs[k][rowg]);
      const float4 bb = *reinterpret_cast<const float4*>(&ws[k][colg]);
      acc[0][0] = fmaf(a.x, bb.x, acc[0][0]);
      acc[0][1] = fmaf(a.x, bb.y, acc[0][1]);
      acc[0][2] = fmaf(a.x, bb.z, acc[0][2]);
      acc[0][3] = fmaf(a.x, bb.w, acc[0][3]);
      acc[1][0] = fmaf(a.y, bb.x, acc[1][0]);
      acc[1][1] = fmaf(a.y, bb.y, acc[1][1]);
      acc[1][2] = fmaf(a.y, bb.z, acc[1][2]);
      acc[1][3] = fmaf(a.y, bb.w, acc[1][3]);
      acc[2][0] = fmaf(a.z, bb.x, acc[2][0]);
      acc[2][1] = fmaf(a.z, bb.y, acc[2][1]);
      acc[2][2] = fmaf(a.z, bb.z, acc[2][2]);
      acc[2][3] = fmaf(a.z, bb.w, acc[2][3]);
      acc[3][0] = fmaf(a.w, bb.x, acc[3][0]);
      acc[3][1] = fmaf(a.w, bb.y, acc[3][1]);
      acc[3][2] = fmaf(a.w, bb.z, acc[3][2]);
      acc[3][3] = fmaf(a.w, bb.w, acc[3][3]);
    }
    __syncthreads();
  }

  // Epilogue: bias + leaky_relu + capsnorm in registers (capsule partner = tid^1)
  const float4 bv = *reinterpret_cast<const float4*>(b + colg);
#pragma unroll
  for (int i = 0; i < 4; ++i) {
    float v0 = acc[i][0] + bv.x;
    float v1 = acc[i][1] + bv.y;
    float v2 = acc[i][2] + bv.z;
    float v3 = acc[i][3] + bv.w;
    v0 = v0 > 0.f ? v0 : SLOPE * v0;
    v1 = v1 > 0.f ? v1 : SLOPE * v1;
    v2 = v2 > 0.f ? v2 : SLOPE * v2;
    v3 = v3 > 0.f ? v3 : SLOPE * v3;
    float s = v0 * v0 + v1 * v1 + v2 * v2 + v3 * v3;
    s += __shfl_xor(s, 1);
    const float inv = 1.0f / fmaxf(sqrtf(s), EPSN);
    const int grow = row0 + rowg + i;
    if (grow < n) {
      float4 o = make_float4(v0 * inv, v1 * inv, v2 * inv, v3 * inv);
      *reinterpret_cast<float4*>(xn + (size_t)grow * 64 + colg) = o;
    }
  }
}

// ---------------------------------------------------------------------------
// CSR construction: counts -> exclusive scan -> cursor scatter
// ---------------------------------------------------------------------------
__global__ __launch_bounds__(256) void zero_int_k(int* __restrict__ p, int n) {
  const int i = blockIdx.x * blockDim.x + threadIdx.x;
  if (i < n) p[i] = 0;
}

__global__ __launch_bounds__(256) void hist_k(const int* __restrict__ trg,
                                              int* __restrict__ counts, int m) {
  const int e = blockIdx.x * blockDim.x + threadIdx.x;
  if (e < m) atomicAdd(&counts[trg[e]], 1);
}

// per-block (256-elem chunk) sums
__global__ __launch_bounds__(256) void scanA_k(const int* __restrict__ counts,
                                               int* __restrict__ bsum, int n) {
  const int i = blockIdx.x * 256 + threadIdx.x;
  int v = (i < n) ? counts[i] : 0;
  v += __shfl_xor(v, 1);  v += __shfl_xor(v, 2);  v += __shfl_xor(v, 4);
  v += __shfl_xor(v, 8);  v += __shfl_xor(v, 16); v += __shfl_xor(v, 32);
  __shared__ int wsum[4];
  if ((threadIdx.x & 63) == 0) wsum[threadIdx.x >> 6] = v;
  __syncthreads();
  if (threadIdx.x == 0) bsum[blockIdx.x] = wsum[0] + wsum[1] + wsum[2] + wsum[3];
}

// serial exclusive scan of block sums (nblk ~ 196); also writes row_ptr[n] = m
__global__ void scanB_k(int* __restrict__ bsum, int nblk, int* __restrict__ row_ptr, int n) {
  if (threadIdx.x == 0 && blockIdx.x == 0) {
    int run = 0;
    for (int i = 0; i < nblk; ++i) { int t = bsum[i]; bsum[i] = run; run += t; }
    row_ptr[n] = run;
  }
}

// intra-chunk exclusive scan + block base; writes row_ptr and cursor
__global__ __launch_bounds__(256) void scanC_k(const int* __restrict__ counts,
                                               const int* __restrict__ bsum,
                                               int* __restrict__ row_ptr,
                                               int* __restrict__ cursor, int n) {
  const int i = blockIdx.x * 256 + threadIdx.x;
  const int lane = threadIdx.x & 63;
  const int wave = threadIdx.x >> 6;
  const int v = (i < n) ? counts[i] : 0;
  int inc = v;
#pragma unroll
  for (int d = 1; d < 64; d <<= 1) {
    int t = __shfl_up(inc, d);
    if (lane >= d) inc += t;
  }
  __shared__ int wsum[4];
  if (lane == 63) wsum[wave] = inc;
  __syncthreads();
  int base = bsum[blockIdx.x];
  for (int w = 0; w < wave; ++w) base += wsum[w];
  const int excl = base + inc - v;
  if (i < n) { row_ptr[i] = excl; cursor[i] = excl; }
}

__global__ __launch_bounds__(256) void scatter_k(const int* __restrict__ src,
                                                 const int* __restrict__ trg,
                                                 int* __restrict__ cursor,
                                                 int* __restrict__ src_sorted, int m) {
  const int e = blockIdx.x * blockDim.x + threadIdx.x;
  if (e < m) {
    const int pos = atomicAdd(&cursor[trg[e]], 1);
    src_sorted[pos] = src[e];
  }
}

// ---------------------------------------------------------------------------
// One routing iteration, wave-per-node, fused (+x, capsnorm, boundary ops).
// MODE 0: dst = capsnorm(acc)                       (iters 0,1)
// MODE 1: dst = capsnorm(lrelu(capsnorm(acc)))      (layer boundary, iter 2)
// MODE 2: dst = lrelu(capsnorm(acc))                (final output, iter 2)
// u[j] is read only by its owner wave -> in-place dst==u is safe.
// ---------------------------------------------------------------------------
template <int MODE>
__global__ __launch_bounds__(256) void rout_node_k(
    const int* __restrict__ row_ptr, const int* __restrict__ src_sorted,
    const float* __restrict__ xn, const float* __restrict__ u,
    float* __restrict__ dst, int n) {
  const int wid  = blockIdx.x * 4 + (threadIdx.x >> 6);
  const int lane = threadIdx.x & 63;
  if (wid >= n) return;

  const float uj = u[(size_t)wid * 64 + lane];
  float acc = xn[(size_t)wid * 64 + lane];   // the "+ x" term

  int e = row_ptr[wid];
  const int end = row_ptr[wid + 1];
  int   s_next = 0;
  float z_next = 0.f;
  if (e < end) { s_next = src_sorted[e]; z_next = xn[(size_t)s_next * 64 + lane]; }
  while (e < end) {
    const float z = z_next;
    ++e;
    if (e < end) { s_next = src_sorted[e]; z_next = xn[(size_t)s_next * 64 + lane]; }
    // per-capsule agreement (8-lane dot)
    float p = z * uj;
    p += __shfl_xor(p, 1);
    p += __shfl_xor(p, 2);
    p += __shfl_xor(p, 4);
    // softmax across 8 capsules (lane bits 3..5), tau = 1
    float mx = p;
    mx = fmaxf(mx, __shfl_xor(mx, 8));
    mx = fmaxf(mx, __shfl_xor(mx, 16));
    mx = fmaxf(mx, __shfl_xor(mx, 32));
    const float ee = __expf(p - mx);
    float sm = ee;
    sm += __shfl_xor(sm, 8);
    sm += __shfl_xor(sm, 16);
    sm += __shfl_xor(sm, 32);
    acc = fmaf(z, ee / sm, acc);
  }

  // capsnorm
  float s2 = acc * acc;
  s2 += __shfl_xor(s2, 1);
  s2 += __shfl_xor(s2, 2);
  s2 += __shfl_xor(s2, 4);
  float v = acc / fmaxf(sqrtf(s2), EPSN);

  if (MODE >= 1) v = v > 0.f ? v : SLOPE * v;     // leaky_relu
  if (MODE == 1) {                                 // re-capsnorm for next layer's x
    float s3 = v * v;
    s3 += __shfl_xor(s3, 1);
    s3 += __shfl_xor(s3, 2);
    s3 += __shfl_xor(s3, 4);
    v = v / fmaxf(sqrtf(s3), EPSN);
  }
  dst[(size_t)wid * 64 + lane] = v;
}

// ---------------------------------------------------------------------------
extern "C" void kernel_launch(void* const* d_in, const int* in_sizes, int n_in,
                              void* d_out, int out_size, void* d_ws, size_t ws_size,
                              hipStream_t stream) {
  const float* x       = (const float*)d_in[0];
  const int*   src_trg = (const int*)d_in[1];
  const float* W       = (const float*)d_in[2];
  const float* b       = (const float*)d_in[3];

  const int hid    = in_sizes[3];          // 64
  const int in_dim = in_sizes[2] / hid;    // 500
  const int n      = in_sizes[0] / in_dim; // 50000
  const int m      = in_sizes[1] / 2;      // 500000
  const int* src = src_trg;
  const int* trg = src_trg + m;

  const size_t n64 = (size_t)n * hid;      // 3.2M floats
  float* xn_a = (float*)d_ws;              // layer-1 normalized features
  float* xn_b = xn_a + n64;                // layer-2 normalized features
  int*   ip   = (int*)(xn_b + n64);
  int* counts     = ip;                    // n
  int* row_ptr    = counts + n;            // n+1
  int* cursor     = row_ptr + n + 1;       // n
  int* bsum       = cursor + n;            // nblk
  const int nblk  = (n + 255) / 256;
  int* src_sorted = bsum + nblk;           // m
  float* ua = (float*)d_out;               // routing state u (owner-only reads -> in-place)

  const int mg = (m + 255) / 256;

  // --- CSR build (once per call) ---
  zero_int_k<<<nblk, 256, 0, stream>>>(counts, n);
  hist_k<<<mg, 256, 0, stream>>>(trg, counts, m);
  scanA_k<<<nblk, 256, 0, stream>>>(counts, bsum, n);
  scanB_k<<<1, 64, 0, stream>>>(bsum, nblk, row_ptr, n);
  scanC_k<<<nblk, 256, 0, stream>>>(counts, bsum, row_ptr, cursor, n);
  scatter_k<<<mg, 256, 0, stream>>>(src, trg, cursor, src_sorted, m);

  // --- xn_a = capsnorm(leaky_relu(x @ W + b)) ---
  gemm_lrelu_capsnorm_k<<<(n + BM - 1) / BM, 256, 0, stream>>>(x, W, b, xn_a, n, in_dim);

  const int rb = (n + 3) / 4;  // 4 waves (nodes) per 256-thread block

  // --- layer 1 ---
  rout_node_k<0><<<rb, 256, 0, stream>>>(row_ptr, src_sorted, xn_a, xn_a, ua, n);
  rout_node_k<0><<<rb, 256, 0, stream>>>(row_ptr, src_sorted, xn_a, ua,   ua, n);
  rout_node_k<1><<<rb, 256, 0, stream>>>(row_ptr, src_sorted, xn_a, ua, xn_b, n);

  // --- layer 2 (final iter writes leaky_relu output straight to d_out) ---
  rout_node_k<0><<<rb, 256, 0, stream>>>(row_ptr, src_sorted, xn_b, xn_b, ua, n);
  rout_node_k<0><<<rb, 256, 0, stream>>>(row_ptr, src_sorted, xn_b, ua,   ua, n);
  rout_node_k<2><<<rb, 256, 0, stream>>>(row_ptr, src_sorted, xn_b, ua,   ua, n);
}

// Round 4
// 321.728 us; speedup vs baseline: 3.6114x; 1.6964x over previous
//
#include <hip/hip_runtime.h>

static constexpr float SLOPE = 0.01f;   // leaky_relu negative_slope
static constexpr float EPSN  = 1e-12f;  // F.normalize eps

#define BM 64     // rows per block
#define BK 50     // k-tile (in_dim = 500 = 10 * 50) -> LDS 25.6 KB -> 6 blocks/CU

// ---------------------------------------------------------------------------
// Fused: xn = capsnorm(leaky_relu(x @ W + b)).  hid = 64, K = 8 capsules of 8.
// 256 threads -> 64 rows x 64 cols, per-thread 4x4 register tile.
// ---------------------------------------------------------------------------
__global__ __launch_bounds__(256) void gemm_lrelu_capsnorm_k(
    const float* __restrict__ x, const float* __restrict__ W,
    const float* __restrict__ b, float* __restrict__ xn, int n, int in_dim) {
  __shared__ float xs[BK][BM];   // transposed x tile: xs[k][row]
  __shared__ float ws[BK][64];   // W tile: ws[k][col]

  const int tid  = threadIdx.x;
  const int row0 = blockIdx.x * BM;
  const int colg = (tid & 15) * 4;   // 16 col-groups of 4
  const int rowg = (tid >> 4) * 4;   // 16 row-groups of 4

  float acc[4][4];
#pragma unroll
  for (int i = 0; i < 4; ++i)
#pragma unroll
    for (int j = 0; j < 4; ++j) acc[i][j] = 0.0f;

  for (int k0 = 0; k0 < in_dim; k0 += BK) {
    // stage x tile (transposed): float2 chunks (BK=50 floats = 25 float2, 8B-aligned)
    // r = idx&63: a wave's lanes hit 64 different rows -> 2-way bank alias (free)
    for (int idx = tid; idx < BM * (BK / 2); idx += 256) {
      const int r  = idx & 63;
      const int kh = idx >> 6;        // float2 chunk 0..24
      float2 v = make_float2(0.f, 0.f);
      const int grow = row0 + r;
      if (grow < n)
        v = *reinterpret_cast<const float2*>(x + (size_t)grow * in_dim + k0 + kh * 2);
      xs[kh * 2 + 0][r] = v.x;
      xs[kh * 2 + 1][r] = v.y;
    }
    // stage W tile: contiguous BK*64 floats (k0*64 float offset, 16B-aligned)
    for (int idx = tid; idx < BK * 64 / 4; idx += 256) {
      *reinterpret_cast<float4*>(&ws[0][0] + idx * 4) =
          *reinterpret_cast<const float4*>(W + (size_t)k0 * 64 + idx * 4);
    }
    __syncthreads();

#pragma unroll 10
    for (int k = 0; k < BK; ++k) {
      const float4 a  = *reinterpret_cast<const float4*>(&xs[k][rowg]);
      const float4 bb = *reinterpret_cast<const float4*>(&ws[k][colg]);
      acc[0][0] = fmaf(a.x, bb.x, acc[0][0]);
      acc[0][1] = fmaf(a.x, bb.y, acc[0][1]);
      acc[0][2] = fmaf(a.x, bb.z, acc[0][2]);
      acc[0][3] = fmaf(a.x, bb.w, acc[0][3]);
      acc[1][0] = fmaf(a.y, bb.x, acc[1][0]);
      acc[1][1] = fmaf(a.y, bb.y, acc[1][1]);
      acc[1][2] = fmaf(a.y, bb.z, acc[1][2]);
      acc[1][3] = fmaf(a.y, bb.w, acc[1][3]);
      acc[2][0] = fmaf(a.z, bb.x, acc[2][0]);
      acc[2][1] = fmaf(a.z, bb.y, acc[2][1]);
      acc[2][2] = fmaf(a.z, bb.z, acc[2][2]);
      acc[2][3] = fmaf(a.z, bb.w, acc[2][3]);
      acc[3][0] = fmaf(a.w, bb.x, acc[3][0]);
      acc[3][1] = fmaf(a.w, bb.y, acc[3][1]);
      acc[3][2] = fmaf(a.w, bb.z, acc[3][2]);
      acc[3][3] = fmaf(a.w, bb.w, acc[3][3]);
    }
    __syncthreads();
  }

  // Epilogue: bias + leaky_relu + capsnorm in registers (capsule partner = tid^1)
  const float4 bv = *reinterpret_cast<const float4*>(b + colg);
#pragma unroll
  for (int i = 0; i < 4; ++i) {
    float v0 = acc[i][0] + bv.x;
    float v1 = acc[i][1] + bv.y;
    float v2 = acc[i][2] + bv.z;
    float v3 = acc[i][3] + bv.w;
    v0 = v0 > 0.f ? v0 : SLOPE * v0;
    v1 = v1 > 0.f ? v1 : SLOPE * v1;
    v2 = v2 > 0.f ? v2 : SLOPE * v2;
    v3 = v3 > 0.f ? v3 : SLOPE * v3;
    float s = v0 * v0 + v1 * v1 + v2 * v2 + v3 * v3;
    s += __shfl_xor(s, 1);
    const float inv = 1.0f / fmaxf(sqrtf(s), EPSN);
    const int grow = row0 + rowg + i;
    if (grow < n) {
      float4 o = make_float4(v0 * inv, v1 * inv, v2 * inv, v3 * inv);
      *reinterpret_cast<float4*>(xn + (size_t)grow * 64 + colg) = o;
    }
  }
}

// ---------------------------------------------------------------------------
// CSR construction: counts -> exclusive scan -> cursor scatter
// ---------------------------------------------------------------------------
__global__ __launch_bounds__(256) void zero_int_k(int* __restrict__ p, int n) {
  const int i = blockIdx.x * blockDim.x + threadIdx.x;
  if (i < n) p[i] = 0;
}

__global__ __launch_bounds__(256) void hist_k(const int* __restrict__ trg,
                                              int* __restrict__ counts, int m) {
  const int e = blockIdx.x * blockDim.x + threadIdx.x;
  if (e < m) atomicAdd(&counts[trg[e]], 1);
}

__global__ __launch_bounds__(256) void scanA_k(const int* __restrict__ counts,
                                               int* __restrict__ bsum, int n) {
  const int i = blockIdx.x * 256 + threadIdx.x;
  int v = (i < n) ? counts[i] : 0;
  v += __shfl_xor(v, 1);  v += __shfl_xor(v, 2);  v += __shfl_xor(v, 4);
  v += __shfl_xor(v, 8);  v += __shfl_xor(v, 16); v += __shfl_xor(v, 32);
  __shared__ int wsum[4];
  if ((threadIdx.x & 63) == 0) wsum[threadIdx.x >> 6] = v;
  __syncthreads();
  if (threadIdx.x == 0) bsum[blockIdx.x] = wsum[0] + wsum[1] + wsum[2] + wsum[3];
}

__global__ void scanB_k(int* __restrict__ bsum, int nblk, int* __restrict__ row_ptr, int n) {
  if (threadIdx.x == 0 && blockIdx.x == 0) {
    int run = 0;
    for (int i = 0; i < nblk; ++i) { int t = bsum[i]; bsum[i] = run; run += t; }
    row_ptr[n] = run;
  }
}

__global__ __launch_bounds__(256) void scanC_k(const int* __restrict__ counts,
                                               const int* __restrict__ bsum,
                                               int* __restrict__ row_ptr,
                                               int* __restrict__ cursor, int n) {
  const int i = blockIdx.x * 256 + threadIdx.x;
  const int lane = threadIdx.x & 63;
  const int wave = threadIdx.x >> 6;
  const int v = (i < n) ? counts[i] : 0;
  int inc = v;
#pragma unroll
  for (int d = 1; d < 64; d <<= 1) {
    int t = __shfl_up(inc, d);
    if (lane >= d) inc += t;
  }
  __shared__ int wsum[4];
  if (lane == 63) wsum[wave] = inc;
  __syncthreads();
  int base = bsum[blockIdx.x];
  for (int w = 0; w < wave; ++w) base += wsum[w];
  const int excl = base + inc - v;
  if (i < n) { row_ptr[i] = excl; cursor[i] = excl; }
}

__global__ __launch_bounds__(256) void scatter_k(const int* __restrict__ src,
                                                 const int* __restrict__ trg,
                                                 int* __restrict__ cursor,
                                                 int* __restrict__ src_sorted, int m) {
  const int e = blockIdx.x * blockDim.x + threadIdx.x;
  if (e < m) {
    const int pos = atomicAdd(&cursor[trg[e]], 1);
    src_sorted[pos] = src[e];
  }
}

// ---------------------------------------------------------------------------
// One routing iteration, wave-per-node, 16 lanes per edge (4 edge slots/wave).
// lane = g*16 + q; g = edge slot, q = float4 chunk (dims 4q..4q+3).
// Capsule c = q>>1 (8 dims = 2 lanes). Per edge: dot = 4 VALU + shfl_xor(1);
// softmax denom = shfl_xor(2,4,8); no max-subtract (|p|<=1: z,u are unit caps).
// MODE 0: dst = capsnorm(acc)
// MODE 1: dst = capsnorm(lrelu(capsnorm(acc)))  (layer boundary)
// MODE 2: dst = lrelu(capsnorm(acc))            (final output)
// u[j] read only by owner wave -> in-place dst==u safe.
// ---------------------------------------------------------------------------
template <int MODE>
__global__ __launch_bounds__(256) void rout_node_k(
    const int* __restrict__ row_ptr, const int* __restrict__ src_sorted,
    const float* __restrict__ xn, const float* __restrict__ u,
    float* __restrict__ dst, int n) {
  const int wid  = blockIdx.x * 4 + (threadIdx.x >> 6);
  const int lane = threadIdx.x & 63;
  if (wid >= n) return;
  const int g = lane >> 4;
  const int q = lane & 15;
  const size_t rowj = (size_t)wid * 64 + q * 4;

  const float4 uj = *reinterpret_cast<const float4*>(u + rowj);
  float4 acc = make_float4(0.f, 0.f, 0.f, 0.f);

  const int e0  = row_ptr[wid];
  const int end = row_ptr[wid + 1];
  const int nt  = (end - e0 + 3) >> 2;

  int e = e0 + g;
  // prefetch slot-0 edge
  bool vn = e < end;
  int  sn = vn ? src_sorted[e] : wid;
  float4 zn = *reinterpret_cast<const float4*>(xn + (size_t)sn * 64 + q * 4);
  if (!vn) zn = make_float4(0.f, 0.f, 0.f, 0.f);

  for (int it = 0; it < nt; ++it) {
    const float4 z = zn;
    e += 4;
    const bool v2 = e < end;
    const int  s2 = v2 ? src_sorted[e] : wid;
    float4 t = *reinterpret_cast<const float4*>(xn + (size_t)s2 * 64 + q * 4);
    zn = v2 ? t : make_float4(0.f, 0.f, 0.f, 0.f);

    // per-capsule agreement p (padded edge: z=0 -> p=0 -> w finite, msg=0)
    float d = z.x * uj.x;
    d = fmaf(z.y, uj.y, d);
    d = fmaf(z.z, uj.z, d);
    d = fmaf(z.w, uj.w, d);
    d += __shfl_xor(d, 1);          // full 8-dim capsule dot
    const float ee = __expf(d);     // |d| <= 1, no max-subtract needed
    float sm = ee;
    sm += __shfl_xor(sm, 2);
    sm += __shfl_xor(sm, 4);
    sm += __shfl_xor(sm, 8);        // sum over the 8 capsules
    const float w = ee * __builtin_amdgcn_rcpf(sm);
    acc.x = fmaf(z.x, w, acc.x);
    acc.y = fmaf(z.y, w, acc.y);
    acc.z = fmaf(z.z, w, acc.z);
    acc.w = fmaf(z.w, w, acc.w);
  }

  // combine the 4 edge slots (lane bits 4,5)
  acc.x += __shfl_xor(acc.x, 16); acc.x += __shfl_xor(acc.x, 32);
  acc.y += __shfl_xor(acc.y, 16); acc.y += __shfl_xor(acc.y, 32);
  acc.z += __shfl_xor(acc.z, 16); acc.z += __shfl_xor(acc.z, 32);
  acc.w += __shfl_xor(acc.w, 16); acc.w += __shfl_xor(acc.w, 32);

  // + x term
  const float4 xj = *reinterpret_cast<const float4*>(xn + rowj);
  acc.x += xj.x; acc.y += xj.y; acc.z += xj.z; acc.w += xj.w;

  // capsnorm
  float ss = acc.x * acc.x + acc.y * acc.y + acc.z * acc.z + acc.w * acc.w;
  ss += __shfl_xor(ss, 1);
  const float inv = 1.0f / fmaxf(sqrtf(ss), EPSN);
  float v0 = acc.x * inv, v1 = acc.y * inv, v2 = acc.z * inv, v3 = acc.w * inv;

  if (MODE >= 1) {   // leaky_relu
    v0 = v0 > 0.f ? v0 : SLOPE * v0;
    v1 = v1 > 0.f ? v1 : SLOPE * v1;
    v2 = v2 > 0.f ? v2 : SLOPE * v2;
    v3 = v3 > 0.f ? v3 : SLOPE * v3;
  }
  if (MODE == 1) {   // re-capsnorm for next layer's x
    float s3 = v0 * v0 + v1 * v1 + v2 * v2 + v3 * v3;
    s3 += __shfl_xor(s3, 1);
    const float inv3 = 1.0f / fmaxf(sqrtf(s3), EPSN);
    v0 *= inv3; v1 *= inv3; v2 *= inv3; v3 *= inv3;
  }
  if (g == 0) {
    *reinterpret_cast<float4*>(dst + rowj) = make_float4(v0, v1, v2, v3);
  }
}

// ---------------------------------------------------------------------------
extern "C" void kernel_launch(void* const* d_in, const int* in_sizes, int n_in,
                              void* d_out, int out_size, void* d_ws, size_t ws_size,
                              hipStream_t stream) {
  const float* x       = (const float*)d_in[0];
  const int*   src_trg = (const int*)d_in[1];
  const float* W       = (const float*)d_in[2];
  const float* b       = (const float*)d_in[3];

  const int hid    = in_sizes[3];          // 64
  const int in_dim = in_sizes[2] / hid;    // 500
  const int n      = in_sizes[0] / in_dim; // 50000
  const int m      = in_sizes[1] / 2;      // 500000
  const int* src = src_trg;
  const int* trg = src_trg + m;

  const size_t n64 = (size_t)n * hid;      // 3.2M floats
  float* xn_a = (float*)d_ws;              // layer-1 normalized features
  float* xn_b = xn_a + n64;                // layer-2 normalized features
  int*   ip   = (int*)(xn_b + n64);
  int* counts     = ip;                    // n
  int* row_ptr    = counts + n;            // n+1
  int* cursor     = row_ptr + n + 1;       // n
  int* bsum       = cursor + n;            // nblk
  const int nblk  = (n + 255) / 256;
  int* src_sorted = bsum + nblk;           // m
  float* ua = (float*)d_out;               // routing state u (owner-only reads)

  const int mg = (m + 255) / 256;

  // --- CSR build (once per call) ---
  zero_int_k<<<nblk, 256, 0, stream>>>(counts, n);
  hist_k<<<mg, 256, 0, stream>>>(trg, counts, m);
  scanA_k<<<nblk, 256, 0, stream>>>(counts, bsum, n);
  scanB_k<<<1, 64, 0, stream>>>(bsum, nblk, row_ptr, n);
  scanC_k<<<nblk, 256, 0, stream>>>(counts, bsum, row_ptr, cursor, n);
  scatter_k<<<mg, 256, 0, stream>>>(src, trg, cursor, src_sorted, m);

  // --- xn_a = capsnorm(leaky_relu(x @ W + b)) ---
  gemm_lrelu_capsnorm_k<<<(n + BM - 1) / BM, 256, 0, stream>>>(x, W, b, xn_a, n, in_dim);

  const int rb = (n + 3) / 4;  // 4 waves (nodes) per 256-thread block

  // --- layer 1 ---
  rout_node_k<0><<<rb, 256, 0, stream>>>(row_ptr, src_sorted, xn_a, xn_a, ua, n);
  rout_node_k<0><<<rb, 256, 0, stream>>>(row_ptr, src_sorted, xn_a, ua,   ua, n);
  rout_node_k<1><<<rb, 256, 0, stream>>>(row_ptr, src_sorted, xn_a, ua, xn_b, n);

  // --- layer 2 (final iter writes leaky_relu output straight to d_out) ---
  rout_node_k<0><<<rb, 256, 0, stream>>>(row_ptr, src_sorted, xn_b, xn_b, ua, n);
  rout_node_k<0><<<rb, 256, 0, stream>>>(row_ptr, src_sorted, xn_b, ua,   ua, n);
  rout_node_k<2><<<rb, 256, 0, stream>>>(row_ptr, src_sorted, xn_b, ua,   ua, n);
}

// Round 5
// 285.244 us; speedup vs baseline: 4.0733x; 1.1279x over previous
//
#include <hip/hip_runtime.h>
#include <hip/hip_bf16.h>

static constexpr float SLOPE = 0.01f;   // leaky_relu negative_slope
static constexpr float EPSN  = 1e-12f;  // F.normalize eps

typedef float f32x4 __attribute__((ext_vector_type(4)));
typedef short short8 __attribute__((ext_vector_type(8)));

#define BM 64        // rows per block (4 waves x 16 rows)
#define KTILE 32     // MFMA K per step
#define KPAD 512     // in_dim = 500 padded to 16 k-tiles

// round-to-nearest bf16 split: v ~= hi + lo, each exactly representable in bf16
__device__ __forceinline__ void bf16_split(float v, short& hi, short& lo) {
  __hip_bfloat16 h = __float2bfloat16(v);
  float hf = __bfloat162float(h);
  __hip_bfloat16 l = __float2bfloat16(v - hf);
  hi = __builtin_bit_cast(short, h);
  lo = __builtin_bit_cast(short, l);
}

// ---------------------------------------------------------------------------
// One-time W prep: split to bf16 hi/lo and swizzle into the MFMA staging
// layout w2[kt][kc][col][8], k zero-padded to KPAD.
// ---------------------------------------------------------------------------
__global__ __launch_bounds__(256) void prep_w_k(const float* __restrict__ W,
                                                short* __restrict__ w2h,
                                                short* __restrict__ w2l, int in_dim) {
  const int idx = blockIdx.x * 256 + threadIdx.x;   // over KPAD*64
  if (idx >= KPAD * 64) return;
  const int k = idx >> 6, col = idx & 63;
  const float v = (k < in_dim) ? W[(size_t)k * 64 + col] : 0.0f;
  short hi, lo;
  bf16_split(v, hi, lo);
  const int kt = k >> 5, kc = (k >> 3) & 3, e = k & 7;
  const int off = (((kt * 4 + kc) * 64) + col) * 8 + e;
  w2h[off] = hi;
  w2l[off] = lo;
}

// ---------------------------------------------------------------------------
// Fused MFMA GEMM: xn = capsnorm(leaky_relu(x @ W + b)).
// 256 thr = 4 waves; wave w owns rows 16w..16w+15, all 64 cols (4 n-tiles).
// Split-bf16: acc += Ah*Bh + Ah*Bl + Al*Bh  (error ~2^-16, fp32-grade).
// Fragment feed: A lane reads xs[kc=l>>4][row=16w+(l&15)][0..8];
//                B lane reads ws[kc=l>>4][col=nt*16+(l&15)][0..8].
// Any internal k-permutation is identical for A and B -> cancels in the dot.
// C/D (verified m89): col = lane&15, row = (lane>>4)*4 + reg.
// ---------------------------------------------------------------------------
__global__ __launch_bounds__(256) void gemm_mfma_capsnorm_k(
    const float* __restrict__ x, const short* __restrict__ w2h,
    const short* __restrict__ w2l, const float* __restrict__ b,
    float* __restrict__ xn, int n, int in_dim) {
  // [kc][idx 0..63][8 bf16] per buffer -> 2048 shorts = 4 KB each, 16 KB total
  __shared__ __align__(16) short xs_h[4 * 64 * 8];
  __shared__ __align__(16) short xs_l[4 * 64 * 8];
  __shared__ __align__(16) short ws_h[4 * 64 * 8];
  __shared__ __align__(16) short ws_l[4 * 64 * 8];

  const int tid  = threadIdx.x;
  const int row0 = blockIdx.x * BM;
  const int w    = tid >> 6;        // wave id
  const int lane = tid & 63;
  const int l15  = lane & 15;
  const int kcL  = lane >> 4;       // lane's k-chunk

  // staging assignment: thread -> (row r, chunk kc)
  const int sr  = tid & 63;
  const int skc = tid >> 6;
  const int sgrow = row0 + sr;
  short* xdh = &xs_h[(skc * 64 + sr) * 8];
  short* xdl = &xs_l[(skc * 64 + sr) * 8];

  // fragment read addresses (constant across k-tiles; single-buffered LDS)
  const short8* pah = reinterpret_cast<const short8*>(&xs_h[(kcL * 64 + 16 * w + l15) * 8]);
  const short8* pal = reinterpret_cast<const short8*>(&xs_l[(kcL * 64 + 16 * w + l15) * 8]);
  const short8* pbh0 = reinterpret_cast<const short8*>(&ws_h[(kcL * 64 + l15) * 8]);
  const short8* pbl0 = reinterpret_cast<const short8*>(&ws_l[(kcL * 64 + l15) * 8]);

  f32x4 acc0 = {0.f, 0.f, 0.f, 0.f};
  f32x4 acc1 = {0.f, 0.f, 0.f, 0.f};
  f32x4 acc2 = {0.f, 0.f, 0.f, 0.f};
  f32x4 acc3 = {0.f, 0.f, 0.f, 0.f};

  const int nkt = (in_dim + KTILE - 1) / KTILE;   // 16
  for (int kt = 0; kt < nkt; ++kt) {
    const int k0 = kt * KTILE;
    // --- stage x tile (fp32 -> split bf16), thread = (sr, skc) ---
    float xv[8];
    const int kb = k0 + skc * 8;
    if (sgrow < n && kb + 8 <= in_dim) {
      const float4 a = *reinterpret_cast<const float4*>(x + (size_t)sgrow * in_dim + kb);
      const float4 c = *reinterpret_cast<const float4*>(x + (size_t)sgrow * in_dim + kb + 4);
      xv[0] = a.x; xv[1] = a.y; xv[2] = a.z; xv[3] = a.w;
      xv[4] = c.x; xv[5] = c.y; xv[6] = c.z; xv[7] = c.w;
    } else {
#pragma unroll
      for (int e = 0; e < 8; ++e) {
        const int k = kb + e;
        xv[e] = (sgrow < n && k < in_dim) ? x[(size_t)sgrow * in_dim + k] : 0.0f;
      }
    }
    short hbuf[8], lbuf[8];
#pragma unroll
    for (int e = 0; e < 8; ++e) bf16_split(xv[e], hbuf[e], lbuf[e]);
    *reinterpret_cast<short8*>(xdh) = *reinterpret_cast<const short8*>(hbuf);
    *reinterpret_cast<short8*>(xdl) = *reinterpret_cast<const short8*>(lbuf);
    // --- stage W tile (pre-split, linear 16B copy) ---
    *reinterpret_cast<short8*>(&ws_h[tid * 8]) =
        *reinterpret_cast<const short8*>(w2h + (size_t)kt * 2048 + tid * 8);
    *reinterpret_cast<short8*>(&ws_l[tid * 8]) =
        *reinterpret_cast<const short8*>(w2l + (size_t)kt * 2048 + tid * 8);
    __syncthreads();

    const short8 ah = *pah;
    const short8 al = *pal;
#pragma unroll
    for (int nt = 0; nt < 4; ++nt) {
      const short8 bh = pbh0[nt * 16];   // +nt*16 idx slots of 8 shorts
      const short8 bl = pbl0[nt * 16];
      f32x4& acc = nt == 0 ? acc0 : nt == 1 ? acc1 : nt == 2 ? acc2 : acc3;
      acc = __builtin_amdgcn_mfma_f32_16x16x32_bf16(ah, bh, acc, 0, 0, 0);
      acc = __builtin_amdgcn_mfma_f32_16x16x32_bf16(ah, bl, acc, 0, 0, 0);
      acc = __builtin_amdgcn_mfma_f32_16x16x32_bf16(al, bh, acc, 0, 0, 0);
    }
    __syncthreads();
  }

  // --- epilogue: bias + leaky_relu + capsnorm, then store ---
  // lane's value (nt, reg): row = row0 + 16w + (lane>>4)*4 + reg, col = nt*16+l15
#pragma unroll
  for (int nt = 0; nt < 4; ++nt) {
    const f32x4 acc = nt == 0 ? acc0 : nt == 1 ? acc1 : nt == 2 ? acc2 : acc3;
    const float bcol = b[nt * 16 + l15];
#pragma unroll
    for (int reg = 0; reg < 4; ++reg) {
      float v = acc[reg] + bcol;
      v = v > 0.f ? v : SLOPE * v;
      float s = v * v;
      s += __shfl_xor(s, 1);
      s += __shfl_xor(s, 2);
      s += __shfl_xor(s, 4);       // capsule sum: 8 cols (lanes sharing l&~7)
      const float inv = 1.0f / fmaxf(sqrtf(s), EPSN);
      const int grow = row0 + 16 * w + ((lane >> 4) << 2) + reg;
      if (grow < n) xn[(size_t)grow * 64 + nt * 16 + l15] = v * inv;
    }
  }
}

// ---------------------------------------------------------------------------
// CSR construction: counts -> exclusive scan -> cursor scatter
// ---------------------------------------------------------------------------
__global__ __launch_bounds__(256) void zero_int_k(int* __restrict__ p, int n) {
  const int i = blockIdx.x * blockDim.x + threadIdx.x;
  if (i < n) p[i] = 0;
}

__global__ __launch_bounds__(256) void hist_k(const int* __restrict__ trg,
                                              int* __restrict__ counts, int m) {
  const int e = blockIdx.x * blockDim.x + threadIdx.x;
  if (e < m) atomicAdd(&counts[trg[e]], 1);
}

__global__ __launch_bounds__(256) void scanA_k(const int* __restrict__ counts,
                                               int* __restrict__ bsum, int n) {
  const int i = blockIdx.x * 256 + threadIdx.x;
  int v = (i < n) ? counts[i] : 0;
  v += __shfl_xor(v, 1);  v += __shfl_xor(v, 2);  v += __shfl_xor(v, 4);
  v += __shfl_xor(v, 8);  v += __shfl_xor(v, 16); v += __shfl_xor(v, 32);
  __shared__ int wsum[4];
  if ((threadIdx.x & 63) == 0) wsum[threadIdx.x >> 6] = v;
  __syncthreads();
  if (threadIdx.x == 0) bsum[blockIdx.x] = wsum[0] + wsum[1] + wsum[2] + wsum[3];
}

__global__ void scanB_k(int* __restrict__ bsum, int nblk, int* __restrict__ row_ptr, int n) {
  if (threadIdx.x == 0 && blockIdx.x == 0) {
    int run = 0;
    for (int i = 0; i < nblk; ++i) { int t = bsum[i]; bsum[i] = run; run += t; }
    row_ptr[n] = run;
  }
}

__global__ __launch_bounds__(256) void scanC_k(const int* __restrict__ counts,
                                               const int* __restrict__ bsum,
                                               int* __restrict__ row_ptr,
                                               int* __restrict__ cursor, int n) {
  const int i = blockIdx.x * 256 + threadIdx.x;
  const int lane = threadIdx.x & 63;
  const int wave = threadIdx.x >> 6;
  const int v = (i < n) ? counts[i] : 0;
  int inc = v;
#pragma unroll
  for (int d = 1; d < 64; d <<= 1) {
    int t = __shfl_up(inc, d);
    if (lane >= d) inc += t;
  }
  __shared__ int wsum[4];
  if (lane == 63) wsum[wave] = inc;
  __syncthreads();
  int base = bsum[blockIdx.x];
  for (int w = 0; w < wave; ++w) base += wsum[w];
  const int excl = base + inc - v;
  if (i < n) { row_ptr[i] = excl; cursor[i] = excl; }
}

__global__ __launch_bounds__(256) void scatter_k(const int* __restrict__ src,
                                                 const int* __restrict__ trg,
                                                 int* __restrict__ cursor,
                                                 int* __restrict__ src_sorted, int m) {
  const int e = blockIdx.x * blockDim.x + threadIdx.x;
  if (e < m) {
    const int pos = atomicAdd(&cursor[trg[e]], 1);
    src_sorted[pos] = src[e];
  }
}

// ---------------------------------------------------------------------------
// One routing iteration, wave-per-node, 16 lanes per edge (4 edge slots/wave).
// MODE 0: dst = capsnorm(acc)
// MODE 1: dst = capsnorm(lrelu(capsnorm(acc)))  (layer boundary)
// MODE 2: dst = lrelu(capsnorm(acc))            (final output)
// ---------------------------------------------------------------------------
template <int MODE>
__global__ __launch_bounds__(256) void rout_node_k(
    const int* __restrict__ row_ptr, const int* __restrict__ src_sorted,
    const float* __restrict__ xn, const float* __restrict__ u,
    float* __restrict__ dst, int n) {
  const int wid  = blockIdx.x * 4 + (threadIdx.x >> 6);
  const int lane = threadIdx.x & 63;
  if (wid >= n) return;
  const int g = lane >> 4;
  const int q = lane & 15;
  const size_t rowj = (size_t)wid * 64 + q * 4;

  const float4 uj = *reinterpret_cast<const float4*>(u + rowj);
  float4 acc = make_float4(0.f, 0.f, 0.f, 0.f);

  const int e0  = row_ptr[wid];
  const int end = row_ptr[wid + 1];
  const int nt  = (end - e0 + 3) >> 2;

  int e = e0 + g;
  bool vn = e < end;
  int  sn = vn ? src_sorted[e] : wid;
  float4 zn = *reinterpret_cast<const float4*>(xn + (size_t)sn * 64 + q * 4);
  if (!vn) zn = make_float4(0.f, 0.f, 0.f, 0.f);

  for (int it = 0; it < nt; ++it) {
    const float4 z = zn;
    e += 4;
    const bool v2 = e < end;
    const int  s2 = v2 ? src_sorted[e] : wid;
    float4 t = *reinterpret_cast<const float4*>(xn + (size_t)s2 * 64 + q * 4);
    zn = v2 ? t : make_float4(0.f, 0.f, 0.f, 0.f);

    float d = z.x * uj.x;
    d = fmaf(z.y, uj.y, d);
    d = fmaf(z.z, uj.z, d);
    d = fmaf(z.w, uj.w, d);
    d += __shfl_xor(d, 1);          // full 8-dim capsule dot
    const float ee = __expf(d);     // |d| <= 1 (unit capsules), no max-sub
    float sm = ee;
    sm += __shfl_xor(sm, 2);
    sm += __shfl_xor(sm, 4);
    sm += __shfl_xor(sm, 8);        // sum over 8 capsules
    const float wgt = ee * __builtin_amdgcn_rcpf(sm);
    acc.x = fmaf(z.x, wgt, acc.x);
    acc.y = fmaf(z.y, wgt, acc.y);
    acc.z = fmaf(z.z, wgt, acc.z);
    acc.w = fmaf(z.w, wgt, acc.w);
  }

  acc.x += __shfl_xor(acc.x, 16); acc.x += __shfl_xor(acc.x, 32);
  acc.y += __shfl_xor(acc.y, 16); acc.y += __shfl_xor(acc.y, 32);
  acc.z += __shfl_xor(acc.z, 16); acc.z += __shfl_xor(acc.z, 32);
  acc.w += __shfl_xor(acc.w, 16); acc.w += __shfl_xor(acc.w, 32);

  const float4 xj = *reinterpret_cast<const float4*>(xn + rowj);
  acc.x += xj.x; acc.y += xj.y; acc.z += xj.z; acc.w += xj.w;

  float ss = acc.x * acc.x + acc.y * acc.y + acc.z * acc.z + acc.w * acc.w;
  ss += __shfl_xor(ss, 1);
  const float inv = 1.0f / fmaxf(sqrtf(ss), EPSN);
  float v0 = acc.x * inv, v1 = acc.y * inv, v2 = acc.z * inv, v3 = acc.w * inv;

  if (MODE >= 1) {
    v0 = v0 > 0.f ? v0 : SLOPE * v0;
    v1 = v1 > 0.f ? v1 : SLOPE * v1;
    v2 = v2 > 0.f ? v2 : SLOPE * v2;
    v3 = v3 > 0.f ? v3 : SLOPE * v3;
  }
  if (MODE == 1) {
    float s3 = v0 * v0 + v1 * v1 + v2 * v2 + v3 * v3;
    s3 += __shfl_xor(s3, 1);
    const float inv3 = 1.0f / fmaxf(sqrtf(s3), EPSN);
    v0 *= inv3; v1 *= inv3; v2 *= inv3; v3 *= inv3;
  }
  if (g == 0) {
    *reinterpret_cast<float4*>(dst + rowj) = make_float4(v0, v1, v2, v3);
  }
}

// ---------------------------------------------------------------------------
extern "C" void kernel_launch(void* const* d_in, const int* in_sizes, int n_in,
                              void* d_out, int out_size, void* d_ws, size_t ws_size,
                              hipStream_t stream) {
  const float* x       = (const float*)d_in[0];
  const int*   src_trg = (const int*)d_in[1];
  const float* W       = (const float*)d_in[2];
  const float* b       = (const float*)d_in[3];

  const int hid    = in_sizes[3];          // 64
  const int in_dim = in_sizes[2] / hid;    // 500
  const int n      = in_sizes[0] / in_dim; // 50000
  const int m      = in_sizes[1] / 2;      // 500000
  const int* src = src_trg;
  const int* trg = src_trg + m;

  const size_t n64 = (size_t)n * hid;      // 3.2M floats
  float* xn_a = (float*)d_ws;              // layer-1 normalized features
  float* xn_b = xn_a + n64;                // layer-2 normalized features
  short* w2h  = (short*)(xn_b + n64);      // KPAD*64 bf16 hi (swizzled)
  short* w2l  = w2h + KPAD * 64;           // KPAD*64 bf16 lo
  int*   ip   = (int*)(w2l + KPAD * 64);
  int* counts     = ip;                    // n
  int* row_ptr    = counts + n;            // n+1
  int* cursor     = row_ptr + n + 1;       // n
  int* bsum       = cursor + n;            // nblk
  const int nblk  = (n + 255) / 256;
  int* src_sorted = bsum + nblk;           // m
  float* ua = (float*)d_out;               // routing state u (owner-only reads)

  const int mg = (m + 255) / 256;

  // --- CSR build (once per call) ---
  zero_int_k<<<nblk, 256, 0, stream>>>(counts, n);
  hist_k<<<mg, 256, 0, stream>>>(trg, counts, m);
  scanA_k<<<nblk, 256, 0, stream>>>(counts, bsum, n);
  scanB_k<<<1, 64, 0, stream>>>(bsum, nblk, row_ptr, n);
  scanC_k<<<nblk, 256, 0, stream>>>(counts, bsum, row_ptr, cursor, n);
  scatter_k<<<mg, 256, 0, stream>>>(src, trg, cursor, src_sorted, m);

  // --- W prep + fused MFMA GEMM: xn_a = capsnorm(lrelu(x @ W + b)) ---
  prep_w_k<<<(KPAD * 64) / 256, 256, 0, stream>>>(W, w2h, w2l, in_dim);
  gemm_mfma_capsnorm_k<<<(n + BM - 1) / BM, 256, 0, stream>>>(
      x, w2h, w2l, b, xn_a, n, in_dim);

  const int rb = (n + 3) / 4;  // 4 waves (nodes) per 256-thread block

  // --- layer 1 ---
  rout_node_k<0><<<rb, 256, 0, stream>>>(row_ptr, src_sorted, xn_a, xn_a, ua, n);
  rout_node_k<0><<<rb, 256, 0, stream>>>(row_ptr, src_sorted, xn_a, ua,   ua, n);
  rout_node_k<1><<<rb, 256, 0, stream>>>(row_ptr, src_sorted, xn_a, ua, xn_b, n);

  // --- layer 2 (final iter writes leaky_relu output straight to d_out) ---
  rout_node_k<0><<<rb, 256, 0, stream>>>(row_ptr, src_sorted, xn_b, xn_b, ua, n);
  rout_node_k<0><<<rb, 256, 0, stream>>>(row_ptr, src_sorted, xn_b, ua,   ua, n);
  rout_node_k<2><<<rb, 256, 0, stream>>>(row_ptr, src_sorted, xn_b, ua,   ua, n);
}

// Round 6
// 194.982 us; speedup vs baseline: 5.9589x; 1.4629x over previous
//
#include <hip/hip_runtime.h>
#include <hip/hip_bf16.h>

static constexpr float SLOPE = 0.01f;   // leaky_relu negative_slope
static constexpr float EPSN  = 1e-12f;  // F.normalize eps

typedef float f32x4 __attribute__((ext_vector_type(4)));
typedef short short8 __attribute__((ext_vector_type(8)));

#define KPAD 512     // in_dim = 500 padded to 16 k-tiles of 32
#define CAP  16      // edges per node cached in LDS for routing iters 2,3

// VALU (DPP) butterfly add: x + shfl_xor(x, 1 or 2) without touching the DS pipe.
// quad_perm[1,0,3,2] = 0xB1 (xor1), quad_perm[2,3,0,1] = 0x4E (xor2).
template <int CTRL>
__device__ __forceinline__ float dpp_xor_add(float x) {
  const int y = __builtin_amdgcn_mov_dpp(__builtin_bit_cast(int, x), CTRL, 0xF, 0xF, true);
  return x + __builtin_bit_cast(float, y);
}

// round-to-nearest bf16 split: v ~= hi + lo, each exactly representable in bf16
__device__ __forceinline__ void bf16_split(float v, short& hi, short& lo) {
  __hip_bfloat16 h = __float2bfloat16(v);
  float hf = __bfloat162float(h);
  __hip_bfloat16 l = __float2bfloat16(v - hf);
  hi = __builtin_bit_cast(short, h);
  lo = __builtin_bit_cast(short, l);
}

// ---------------------------------------------------------------------------
// One-time W prep: split to bf16 hi/lo, swizzle to w2[kt][kc][col][8], zero-pad k.
// ---------------------------------------------------------------------------
__global__ __launch_bounds__(256) void prep_w_k(const float* __restrict__ W,
                                                short* __restrict__ w2h,
                                                short* __restrict__ w2l, int in_dim) {
  const int idx = blockIdx.x * 256 + threadIdx.x;   // over KPAD*64
  if (idx >= KPAD * 64) return;
  const int k = idx >> 6, col = idx & 63;
  const float v = (k < in_dim) ? W[(size_t)k * 64 + col] : 0.0f;
  short hi, lo;
  bf16_split(v, hi, lo);
  const int kt = k >> 5, kc = (k >> 3) & 3, e = k & 7;
  const int off = (((kt * 4 + kc) * 64) + col) * 8 + e;
  w2h[off] = hi;
  w2l[off] = lo;
}

// ---------------------------------------------------------------------------
// Fused MFMA GEMM: xn = capsnorm(leaky_relu(x @ W + b)).
// Barrier-free main loop: A-fragments loaded straight from global x (8
// consecutive k-floats per lane), B-fragments from pre-swizzled w2h/w2l
// (L2-resident). 4 waves/block = 2 row-groups x 2 k-halves (split-K),
// combined once through 8 KB LDS. Grid 2x denser than round 5.
// C/D mapping (verified m89): col = lane&15, row = (lane>>4)*4 + reg.
// ---------------------------------------------------------------------------
__global__ __launch_bounds__(256) void gemm_mfma_capsnorm_k(
    const float* __restrict__ x, const short* __restrict__ w2h,
    const short* __restrict__ w2l, const float* __restrict__ b,
    float* __restrict__ xn, int n, int in_dim) {
  __shared__ float psum[2][4][256];   // [row-group][nt][lane*4] k-half partials

  const int tid  = threadIdx.x;
  const int lane = tid & 63;
  const int w    = tid >> 6;
  const int rg   = w >> 1;            // row-group 0..1
  const int kh   = w & 1;             // k-half 0..1
  const int l15  = lane & 15;
  const int kcL  = lane >> 4;
  const int row0 = blockIdx.x * 32 + rg * 16;
  const int myrow = row0 + l15;
  const bool rowok = myrow < n;
  const float* xrow = x + (size_t)myrow * in_dim;

  f32x4 acc0 = {0.f, 0.f, 0.f, 0.f};
  f32x4 acc1 = {0.f, 0.f, 0.f, 0.f};
  f32x4 acc2 = {0.f, 0.f, 0.f, 0.f};
  f32x4 acc3 = {0.f, 0.f, 0.f, 0.f};

#pragma unroll 2
  for (int kti = 0; kti < 8; ++kti) {
    const int kt = kh * 8 + kti;
    const int kb = kt * 32 + kcL * 8;
    // --- A fragment: x[myrow][kb..kb+8), split to bf16 hi/lo in registers ---
    float xv[8];
    if (rowok && kb + 8 <= in_dim) {
      const float4 a = *reinterpret_cast<const float4*>(xrow + kb);
      const float4 c = *reinterpret_cast<const float4*>(xrow + kb + 4);
      xv[0] = a.x; xv[1] = a.y; xv[2] = a.z; xv[3] = a.w;
      xv[4] = c.x; xv[5] = c.y; xv[6] = c.z; xv[7] = c.w;
    } else {
#pragma unroll
      for (int e = 0; e < 8; ++e) {
        const int k = kb + e;
        xv[e] = (rowok && k < in_dim) ? xrow[k] : 0.0f;
      }
    }
    short hb[8], lb[8];
#pragma unroll
    for (int e = 0; e < 8; ++e) bf16_split(xv[e], hb[e], lb[e]);
    const short8 ah = *reinterpret_cast<const short8*>(hb);
    const short8 al = *reinterpret_cast<const short8*>(lb);
    // --- B fragments from pre-swizzled global (per nt) + 3-term MFMA ---
    const size_t base = ((size_t)(kt * 4 + kcL) * 64) * 8;
#pragma unroll
    for (int nt = 0; nt < 4; ++nt) {
      const short8 bh = *reinterpret_cast<const short8*>(w2h + base + (size_t)(nt * 16 + l15) * 8);
      const short8 bl = *reinterpret_cast<const short8*>(w2l + base + (size_t)(nt * 16 + l15) * 8);
      f32x4& acc = nt == 0 ? acc0 : nt == 1 ? acc1 : nt == 2 ? acc2 : acc3;
      acc = __builtin_amdgcn_mfma_f32_16x16x32_bf16(ah, bh, acc, 0, 0, 0);
      acc = __builtin_amdgcn_mfma_f32_16x16x32_bf16(ah, bl, acc, 0, 0, 0);
      acc = __builtin_amdgcn_mfma_f32_16x16x32_bf16(al, bh, acc, 0, 0, 0);
    }
  }

  // --- split-K combine through LDS ---
  if (kh == 1) {
    *reinterpret_cast<f32x4*>(&psum[rg][0][lane * 4]) = acc0;
    *reinterpret_cast<f32x4*>(&psum[rg][1][lane * 4]) = acc1;
    *reinterpret_cast<f32x4*>(&psum[rg][2][lane * 4]) = acc2;
    *reinterpret_cast<f32x4*>(&psum[rg][3][lane * 4]) = acc3;
  }
  __syncthreads();
  if (kh == 1) return;
  acc0 += *reinterpret_cast<const f32x4*>(&psum[rg][0][lane * 4]);
  acc1 += *reinterpret_cast<const f32x4*>(&psum[rg][1][lane * 4]);
  acc2 += *reinterpret_cast<const f32x4*>(&psum[rg][2][lane * 4]);
  acc3 += *reinterpret_cast<const f32x4*>(&psum[rg][3][lane * 4]);

  // --- epilogue: bias + leaky_relu + capsnorm (capsule = 8 cols, xor 1,2,4) ---
#pragma unroll
  for (int nt = 0; nt < 4; ++nt) {
    const f32x4 acc = nt == 0 ? acc0 : nt == 1 ? acc1 : nt == 2 ? acc2 : acc3;
    const float bcol = b[nt * 16 + l15];
#pragma unroll
    for (int reg = 0; reg < 4; ++reg) {
      float v = acc[reg] + bcol;
      v = v > 0.f ? v : SLOPE * v;
      float s = v * v;
      s = dpp_xor_add<0xB1>(s);    // xor 1 (VALU)
      s = dpp_xor_add<0x4E>(s);    // xor 2 (VALU)
      s += __shfl_xor(s, 4);
      const float inv = 1.0f / fmaxf(sqrtf(s), EPSN);
      const int grow = row0 + ((lane >> 4) << 2) + reg;
      if (grow < n) xn[(size_t)grow * 64 + nt * 16 + l15] = v * inv;
    }
  }
}

// ---------------------------------------------------------------------------
// CSR construction: counts -> exclusive scan -> cursor scatter
// ---------------------------------------------------------------------------
__global__ __launch_bounds__(256) void zero_int_k(int* __restrict__ p, int n) {
  const int i = blockIdx.x * blockDim.x + threadIdx.x;
  if (i < n) p[i] = 0;
}

__global__ __launch_bounds__(256) void hist_k(const int* __restrict__ trg,
                                              int* __restrict__ counts, int m) {
  const int e = blockIdx.x * blockDim.x + threadIdx.x;
  if (e < m) atomicAdd(&counts[trg[e]], 1);
}

__global__ __launch_bounds__(256) void scanA_k(const int* __restrict__ counts,
                                               int* __restrict__ bsum, int n) {
  const int i = blockIdx.x * 256 + threadIdx.x;
  int v = (i < n) ? counts[i] : 0;
  v += __shfl_xor(v, 1);  v += __shfl_xor(v, 2);  v += __shfl_xor(v, 4);
  v += __shfl_xor(v, 8);  v += __shfl_xor(v, 16); v += __shfl_xor(v, 32);
  __shared__ int wsum[4];
  if ((threadIdx.x & 63) == 0) wsum[threadIdx.x >> 6] = v;
  __syncthreads();
  if (threadIdx.x == 0) bsum[blockIdx.x] = wsum[0] + wsum[1] + wsum[2] + wsum[3];
}

__global__ void scanB_k(int* __restrict__ bsum, int nblk, int* __restrict__ row_ptr, int n) {
  if (threadIdx.x == 0 && blockIdx.x == 0) {
    int run = 0;
    for (int i = 0; i < nblk; ++i) { int t = bsum[i]; bsum[i] = run; run += t; }
    row_ptr[n] = run;
  }
}

__global__ __launch_bounds__(256) void scanC_k(const int* __restrict__ counts,
                                               const int* __restrict__ bsum,
                                               int* __restrict__ row_ptr,
                                               int* __restrict__ cursor, int n) {
  const int i = blockIdx.x * 256 + threadIdx.x;
  const int lane = threadIdx.x & 63;
  const int wave = threadIdx.x >> 6;
  const int v = (i < n) ? counts[i] : 0;
  int inc = v;
#pragma unroll
  for (int d = 1; d < 64; d <<= 1) {
    int t = __shfl_up(inc, d);
    if (lane >= d) inc += t;
  }
  __shared__ int wsum[4];
  if (lane == 63) wsum[wave] = inc;
  __syncthreads();
  int base = bsum[blockIdx.x];
  for (int w = 0; w < wave; ++w) base += wsum[w];
  const int excl = base + inc - v;
  if (i < n) { row_ptr[i] = excl; cursor[i] = excl; }
}

__global__ __launch_bounds__(256) void scatter_k(const int* __restrict__ src,
                                                 const int* __restrict__ trg,
                                                 int* __restrict__ cursor,
                                                 int* __restrict__ src_sorted, int m) {
  const int e = blockIdx.x * blockDim.x + threadIdx.x;
  if (e < m) {
    const int pos = atomicAdd(&cursor[trg[e]], 1);
    src_sorted[pos] = src[e];
  }
}

// ---------------------------------------------------------------------------
// One FULL routing layer (3 iterations fused), wave-per-node, 16 lanes/edge.
// u lives in registers across iterations (owner-wave-only access). z gathered
// from global once (t=0), first CAP edges cached in per-wave LDS; overflow
// edges (deg > CAP, ~3%) re-gathered. xor1/xor2 reduces via VALU DPP.
// MODE 1: dst = capsnorm(lrelu(u3))   (layer boundary -> next layer's xn)
// MODE 2: dst = lrelu(u3)             (final output)
// ---------------------------------------------------------------------------
template <int MODE>
__global__ __launch_bounds__(256) void rout_layer_k(
    const int* __restrict__ row_ptr, const int* __restrict__ src_sorted,
    const float* __restrict__ xn, float* __restrict__ dst, int n) {
  __shared__ float zc[4][CAP * 64];
  const int wv   = threadIdx.x >> 6;
  const int wid  = blockIdx.x * 4 + wv;
  const int lane = threadIdx.x & 63;
  if (wid >= n) return;
  const int g = lane >> 4;          // edge slot 0..3
  const int q = lane & 15;          // float4 chunk (dims 4q..4q+3)
  const size_t rowj = (size_t)wid * 64 + q * 4;
  float* zbase = &zc[wv][0];

  const float4 xj = *reinterpret_cast<const float4*>(xn + rowj);
  float u0 = xj.x, u1 = xj.y, u2 = xj.z, u3 = xj.w;   // u = x initially

  const int e0  = row_ptr[wid];
  const int end = row_ptr[wid + 1];
  const int ntile = (end - e0 + 3) >> 2;

  for (int t = 0; t < 3; ++t) {
    float a0 = 0.f, a1 = 0.f, a2 = 0.f, a3 = 0.f;

#define EDGE_BODY(Z)                                                   \
    {                                                                  \
      float d = (Z).x * u0;                                            \
      d = fmaf((Z).y, u1, d);                                          \
      d = fmaf((Z).z, u2, d);                                          \
      d = fmaf((Z).w, u3, d);                                          \
      d = dpp_xor_add<0xB1>(d);          /* 8-dim capsule dot */       \
      const float ee = __expf(d);        /* |d|<=1: unit capsules */   \
      float sm = dpp_xor_add<0x4E>(ee);                                \
      sm += __shfl_xor(sm, 4);                                         \
      sm += __shfl_xor(sm, 8);           /* sum over 8 capsules */     \
      const float wgt = ee * __builtin_amdgcn_rcpf(sm);                \
      a0 = fmaf((Z).x, wgt, a0);                                       \
      a1 = fmaf((Z).y, wgt, a1);                                       \
      a2 = fmaf((Z).z, wgt, a2);                                       \
      a3 = fmaf((Z).w, wgt, a3);                                       \
    }

    if (t == 0) {
      int e = e0 + g;
      bool vn = e < end;
      int  sn = vn ? src_sorted[e] : wid;
      float4 zn = *reinterpret_cast<const float4*>(xn + (size_t)sn * 64 + q * 4);
      if (!vn) zn = make_float4(0.f, 0.f, 0.f, 0.f);
      for (int it = 0; it < ntile; ++it) {
        const float4 z = zn;
        e += 4;
        const bool v2 = e < end;
        const int  s2 = v2 ? src_sorted[e] : wid;
        float4 tz = *reinterpret_cast<const float4*>(xn + (size_t)s2 * 64 + q * 4);
        zn = v2 ? tz : make_float4(0.f, 0.f, 0.f, 0.f);
        const int slot = it * 4 + g;
        if (slot < CAP)
          *reinterpret_cast<float4*>(zbase + slot * 64 + q * 4) = z;
        EDGE_BODY(z)
      }
    } else {
      for (int it = 0; it < ntile; ++it) {
        const int slot = it * 4 + g;
        float4 z;
        if (slot < CAP) {
          z = *reinterpret_cast<const float4*>(zbase + slot * 64 + q * 4);
        } else {
          const int e = e0 + slot;
          const bool vv = e < end;
          const int ss = vv ? src_sorted[e] : wid;
          z = *reinterpret_cast<const float4*>(xn + (size_t)ss * 64 + q * 4);
          if (!vv) z = make_float4(0.f, 0.f, 0.f, 0.f);
        }
        EDGE_BODY(z)
      }
    }
#undef EDGE_BODY

    // combine the 4 edge slots (lane bits 4,5)
    a0 += __shfl_xor(a0, 16); a0 += __shfl_xor(a0, 32);
    a1 += __shfl_xor(a1, 16); a1 += __shfl_xor(a1, 32);
    a2 += __shfl_xor(a2, 16); a2 += __shfl_xor(a2, 32);
    a3 += __shfl_xor(a3, 16); a3 += __shfl_xor(a3, 32);
    // + x, capsnorm -> next u (all lanes hold the full sums)
    a0 += xj.x; a1 += xj.y; a2 += xj.z; a3 += xj.w;
    float ss = a0 * a0 + a1 * a1 + a2 * a2 + a3 * a3;
    ss = dpp_xor_add<0xB1>(ss);
    const float inv = 1.0f / fmaxf(sqrtf(ss), EPSN);
    u0 = a0 * inv; u1 = a1 * inv; u2 = a2 * inv; u3 = a3 * inv;
  }

  // boundary transforms
  float v0 = u0, v1 = u1, v2 = u2, v3 = u3;
  v0 = v0 > 0.f ? v0 : SLOPE * v0;
  v1 = v1 > 0.f ? v1 : SLOPE * v1;
  v2 = v2 > 0.f ? v2 : SLOPE * v2;
  v3 = v3 > 0.f ? v3 : SLOPE * v3;
  if (MODE == 1) {   // re-capsnorm for next layer's x
    float s3 = v0 * v0 + v1 * v1 + v2 * v2 + v3 * v3;
    s3 = dpp_xor_add<0xB1>(s3);
    const float inv3 = 1.0f / fmaxf(sqrtf(s3), EPSN);
    v0 *= inv3; v1 *= inv3; v2 *= inv3; v3 *= inv3;
  }
  if (g == 0) {
    *reinterpret_cast<float4*>(dst + rowj) = make_float4(v0, v1, v2, v3);
  }
}

// ---------------------------------------------------------------------------
extern "C" void kernel_launch(void* const* d_in, const int* in_sizes, int n_in,
                              void* d_out, int out_size, void* d_ws, size_t ws_size,
                              hipStream_t stream) {
  const float* x       = (const float*)d_in[0];
  const int*   src_trg = (const int*)d_in[1];
  const float* W       = (const float*)d_in[2];
  const float* b       = (const float*)d_in[3];

  const int hid    = in_sizes[3];          // 64
  const int in_dim = in_sizes[2] / hid;    // 500
  const int n      = in_sizes[0] / in_dim; // 50000
  const int m      = in_sizes[1] / 2;      // 500000
  const int* src = src_trg;
  const int* trg = src_trg + m;

  const size_t n64 = (size_t)n * hid;      // 3.2M floats
  float* xn_a = (float*)d_ws;              // layer-1 normalized features
  float* xn_b = xn_a + n64;                // layer-2 normalized features
  short* w2h  = (short*)(xn_b + n64);      // KPAD*64 bf16 hi (swizzled)
  short* w2l  = w2h + KPAD * 64;           // KPAD*64 bf16 lo
  int*   ip   = (int*)(w2l + KPAD * 64);
  int* counts     = ip;                    // n
  int* row_ptr    = counts + n;            // n+1
  int* cursor     = row_ptr + n + 1;       // n
  int* bsum       = cursor + n;            // nblk
  const int nblk  = (n + 255) / 256;
  int* src_sorted = bsum + nblk;           // m
  float* out = (float*)d_out;

  const int mg = (m + 255) / 256;

  // --- CSR build (once per call) ---
  zero_int_k<<<nblk, 256, 0, stream>>>(counts, n);
  hist_k<<<mg, 256, 0, stream>>>(trg, counts, m);
  scanA_k<<<nblk, 256, 0, stream>>>(counts, bsum, n);
  scanB_k<<<1, 64, 0, stream>>>(bsum, nblk, row_ptr, n);
  scanC_k<<<nblk, 256, 0, stream>>>(counts, bsum, row_ptr, cursor, n);
  scatter_k<<<mg, 256, 0, stream>>>(src, trg, cursor, src_sorted, m);

  // --- W prep + fused MFMA GEMM: xn_a = capsnorm(lrelu(x @ W + b)) ---
  prep_w_k<<<(KPAD * 64) / 256, 256, 0, stream>>>(W, w2h, w2l, in_dim);
  gemm_mfma_capsnorm_k<<<(n + 31) / 32, 256, 0, stream>>>(
      x, w2h, w2l, b, xn_a, n, in_dim);

  // --- routing: one fused kernel per layer (3 iterations each) ---
  const int rb = (n + 3) / 4;  // 4 waves (nodes) per 256-thread block
  rout_layer_k<1><<<rb, 256, 0, stream>>>(row_ptr, src_sorted, xn_a, xn_b, n);
  rout_layer_k<2><<<rb, 256, 0, stream>>>(row_ptr, src_sorted, xn_b, out, n);
}

// Round 7
// 180.528 us; speedup vs baseline: 6.4360x; 1.0801x over previous
//
#include <hip/hip_runtime.h>
#include <hip/hip_bf16.h>

static constexpr float SLOPE = 0.01f;   // leaky_relu negative_slope
static constexpr float EPSN  = 1e-12f;  // F.normalize eps

typedef float f32x4 __attribute__((ext_vector_type(4)));
typedef short short8 __attribute__((ext_vector_type(8)));

#define KPAD 512     // in_dim = 500 padded to 16 k-tiles of 32
#define CAP  16      // edges per node cached in LDS for routing iters 2,3
#define XSTRIDE 260  // LDS row stride in floats (256 + 4 pad) -> conflict-free b128

// VALU (DPP) butterfly/rotate add: x + dpp(x). No DS-pipe traffic.
// quad_perm[1,0,3,2]=0xB1 (xor1), quad_perm[2,3,0,1]=0x4E (xor2),
// row_ror:4=0x124, row_ror:8=0x128 (rotate within 16-lane row).
template <int CTRL>
__device__ __forceinline__ float dpp_add(float x) {
  const int y = __builtin_amdgcn_mov_dpp(__builtin_bit_cast(int, x), CTRL, 0xF, 0xF, true);
  return x + __builtin_bit_cast(float, y);
}

// round-to-nearest bf16 split: v ~= hi + lo, each exactly representable in bf16
__device__ __forceinline__ void bf16_split(float v, short& hi, short& lo) {
  __hip_bfloat16 h = __float2bfloat16(v);
  float hf = __bfloat162float(h);
  __hip_bfloat16 l = __float2bfloat16(v - hf);
  hi = __builtin_bit_cast(short, h);
  lo = __builtin_bit_cast(short, l);
}

// ---------------------------------------------------------------------------
// One-time W prep: split to bf16 hi/lo, swizzle to w2[kt][kc][col][8], zero-pad k.
// ---------------------------------------------------------------------------
__global__ __launch_bounds__(256) void prep_w_k(const float* __restrict__ W,
                                                short* __restrict__ w2h,
                                                short* __restrict__ w2l, int in_dim) {
  const int idx = blockIdx.x * 256 + threadIdx.x;   // over KPAD*64
  if (idx >= KPAD * 64) return;
  const int k = idx >> 6, col = idx & 63;
  const float v = (k < in_dim) ? W[(size_t)k * 64 + col] : 0.0f;
  short hi, lo;
  bf16_split(v, hi, lo);
  const int kt = k >> 5, kc = (k >> 3) & 3, e = k & 7;
  const int off = (((kt * 4 + kc) * 64) + col) * 8 + e;
  w2h[off] = hi;
  w2l[off] = lo;
}

// ---------------------------------------------------------------------------
// Fused MFMA GEMM: xn = capsnorm(leaky_relu(x @ W + b)).
// 64 rows/block, 4 waves x 16 rows, 2 k-chunks of 256.
// x tile staged to LDS with row-contiguous COALESCED 1KB wave reads
// (fixes the scattered 16B/lane A-fetch that saturated the L1/TA path),
// fragments then read as ds_read_b128 (stride 260 floats: conflict-free).
// B fragments from pre-swizzled w2h/w2l (L2-resident, contiguous 1KB/instr).
// Split-bf16: acc += Ah*Bh + Ah*Bl + Al*Bh. C/D: col=lane&15, row=(lane>>4)*4+reg.
// ---------------------------------------------------------------------------
__global__ __launch_bounds__(256) void gemm_mfma_capsnorm_k(
    const float* __restrict__ x, const short* __restrict__ w2h,
    const short* __restrict__ w2l, const float* __restrict__ b,
    float* __restrict__ xn, int n, int in_dim) {
  __shared__ __align__(16) float xs[64 * XSTRIDE];   // 66,560 B

  const int tid  = threadIdx.x;
  const int lane = tid & 63;
  const int w    = tid >> 6;
  const int l15  = lane & 15;
  const int kcL  = lane >> 4;
  const int row0 = blockIdx.x * 64;

  f32x4 acc0 = {0.f, 0.f, 0.f, 0.f};
  f32x4 acc1 = {0.f, 0.f, 0.f, 0.f};
  f32x4 acc2 = {0.f, 0.f, 0.f, 0.f};
  f32x4 acc3 = {0.f, 0.f, 0.f, 0.f};

  const float* xfrag = &xs[(w * 16 + l15) * XSTRIDE + kcL * 8];

  for (int chunk = 0; chunk < 2; ++chunk) {
    const int kbase = chunk * 256;
    // --- stage 64 rows x 256 k: wave reads 1KB contiguous per instruction ---
#pragma unroll 4
    for (int off = 0; off < 16; ++off) {
      const int idx = off * 256 + tid;
      const int r = idx >> 6;          // row in tile (wave-uniform per instr)
      const int c = idx & 63;          // float4 index within chunk
      const int grow = row0 + r;
      const int k = kbase + c * 4;
      float4 v = make_float4(0.f, 0.f, 0.f, 0.f);
      if (grow < n && k + 3 < in_dim)
        v = *reinterpret_cast<const float4*>(x + (size_t)grow * in_dim + k);
      *reinterpret_cast<float4*>(&xs[r * XSTRIDE + c * 4]) = v;
    }
    __syncthreads();

    // --- 8 k-tiles of 32 ---
#pragma unroll 2
    for (int ktl = 0; ktl < 8; ++ktl) {
      const float4 a  = *reinterpret_cast<const float4*>(xfrag + ktl * 32);
      const float4 c4 = *reinterpret_cast<const float4*>(xfrag + ktl * 32 + 4);
      short hb[8], lb[8];
      bf16_split(a.x,  hb[0], lb[0]);
      bf16_split(a.y,  hb[1], lb[1]);
      bf16_split(a.z,  hb[2], lb[2]);
      bf16_split(a.w,  hb[3], lb[3]);
      bf16_split(c4.x, hb[4], lb[4]);
      bf16_split(c4.y, hb[5], lb[5]);
      bf16_split(c4.z, hb[6], lb[6]);
      bf16_split(c4.w, hb[7], lb[7]);
      const short8 ah = *reinterpret_cast<const short8*>(hb);
      const short8 al = *reinterpret_cast<const short8*>(lb);
      const int ktg = chunk * 8 + ktl;
      const size_t base = ((size_t)(ktg * 4 + kcL) * 64) * 8;
#pragma unroll
      for (int nt = 0; nt < 4; ++nt) {
        const short8 bh = *reinterpret_cast<const short8*>(w2h + base + (size_t)(nt * 16 + l15) * 8);
        const short8 bl = *reinterpret_cast<const short8*>(w2l + base + (size_t)(nt * 16 + l15) * 8);
        f32x4& acc = nt == 0 ? acc0 : nt == 1 ? acc1 : nt == 2 ? acc2 : acc3;
        acc = __builtin_amdgcn_mfma_f32_16x16x32_bf16(ah, bh, acc, 0, 0, 0);
        acc = __builtin_amdgcn_mfma_f32_16x16x32_bf16(ah, bl, acc, 0, 0, 0);
        acc = __builtin_amdgcn_mfma_f32_16x16x32_bf16(al, bh, acc, 0, 0, 0);
      }
    }
    __syncthreads();
  }

  // --- epilogue: bias + leaky_relu + capsnorm (capsule = 8 cols) ---
#pragma unroll
  for (int nt = 0; nt < 4; ++nt) {
    const f32x4 acc = nt == 0 ? acc0 : nt == 1 ? acc1 : nt == 2 ? acc2 : acc3;
    const float bcol = b[nt * 16 + l15];
#pragma unroll
    for (int reg = 0; reg < 4; ++reg) {
      float v = acc[reg] + bcol;
      v = v > 0.f ? v : SLOPE * v;
      float s = v * v;
      s = dpp_add<0xB1>(s);        // xor1 (VALU)
      s = dpp_add<0x4E>(s);        // xor2 (VALU)
      s += __shfl_xor(s, 4);       // xor4 (crosses 8-lane halves; DS)
      const float inv = 1.0f / fmaxf(sqrtf(s), EPSN);
      const int grow = row0 + w * 16 + ((lane >> 4) << 2) + reg;
      if (grow < n) xn[(size_t)grow * 64 + nt * 16 + l15] = v * inv;
    }
  }
}

// ---------------------------------------------------------------------------
// CSR construction: counts -> exclusive scan -> cursor scatter
// ---------------------------------------------------------------------------
__global__ __launch_bounds__(256) void zero_int_k(int* __restrict__ p, int n) {
  const int i = blockIdx.x * blockDim.x + threadIdx.x;
  if (i < n) p[i] = 0;
}

__global__ __launch_bounds__(256) void hist_k(const int* __restrict__ trg,
                                              int* __restrict__ counts, int m) {
  const int e = blockIdx.x * blockDim.x + threadIdx.x;
  if (e < m) atomicAdd(&counts[trg[e]], 1);
}

__global__ __launch_bounds__(256) void scanA_k(const int* __restrict__ counts,
                                               int* __restrict__ bsum, int n) {
  const int i = blockIdx.x * 256 + threadIdx.x;
  int v = (i < n) ? counts[i] : 0;
  v += __shfl_xor(v, 1);  v += __shfl_xor(v, 2);  v += __shfl_xor(v, 4);
  v += __shfl_xor(v, 8);  v += __shfl_xor(v, 16); v += __shfl_xor(v, 32);
  __shared__ int wsum[4];
  if ((threadIdx.x & 63) == 0) wsum[threadIdx.x >> 6] = v;
  __syncthreads();
  if (threadIdx.x == 0) bsum[blockIdx.x] = wsum[0] + wsum[1] + wsum[2] + wsum[3];
}

// PARALLEL exclusive scan of block sums (nblk <= 256; n=50000 -> nblk=196).
// Replaces the serial single-thread scan (~30us of dependent L2 RMW latency).
__global__ __launch_bounds__(256) void scanB_k(int* __restrict__ bsum, int nblk,
                                               int* __restrict__ row_ptr, int n, int m) {
  const int i = threadIdx.x;
  const int lane = i & 63;
  const int wave = i >> 6;
  const int v = (i < nblk) ? bsum[i] : 0;
  int inc = v;
#pragma unroll
  for (int d = 1; d < 64; d <<= 1) {
    int t = __shfl_up(inc, d);
    if (lane >= d) inc += t;
  }
  __shared__ int wsum[4];
  if (lane == 63) wsum[wave] = inc;
  __syncthreads();
  int base = 0;
  for (int q = 0; q < wave; ++q) base += wsum[q];
  if (i < nblk) bsum[i] = base + inc - v;
  if (i == 0) row_ptr[n] = m;
}

__global__ __launch_bounds__(256) void scanC_k(const int* __restrict__ counts,
                                               const int* __restrict__ bsum,
                                               int* __restrict__ row_ptr,
                                               int* __restrict__ cursor, int n) {
  const int i = blockIdx.x * 256 + threadIdx.x;
  const int lane = threadIdx.x & 63;
  const int wave = threadIdx.x >> 6;
  const int v = (i < n) ? counts[i] : 0;
  int inc = v;
#pragma unroll
  for (int d = 1; d < 64; d <<= 1) {
    int t = __shfl_up(inc, d);
    if (lane >= d) inc += t;
  }
  __shared__ int wsum[4];
  if (lane == 63) wsum[wave] = inc;
  __syncthreads();
  int base = bsum[blockIdx.x];
  for (int q = 0; q < wave; ++q) base += wsum[q];
  const int excl = base + inc - v;
  if (i < n) { row_ptr[i] = excl; cursor[i] = excl; }
}

__global__ __launch_bounds__(256) void scatter_k(const int* __restrict__ src,
                                                 const int* __restrict__ trg,
                                                 int* __restrict__ cursor,
                                                 int* __restrict__ src_sorted, int m) {
  const int e = blockIdx.x * blockDim.x + threadIdx.x;
  if (e < m) {
    const int pos = atomicAdd(&cursor[trg[e]], 1);
    src_sorted[pos] = src[e];
  }
}

// ---------------------------------------------------------------------------
// One FULL routing layer (3 iterations fused), wave-per-node, 16 lanes/edge.
// u in registers across iterations; z gathered once (t=0), first CAP edges
// cached in per-wave LDS; overflow re-gathered. Softmax denominator reduce is
// ALL-VALU DPP: xor2 (quad_perm 0x4E) + row_ror:4 + row_ror:8 covers each of
// the 8 capsules exactly once ({c,c^1}+{0,2,4,6} mod 8). Zero DS ops per edge.
// MODE 1: dst = capsnorm(lrelu(u3))   (layer boundary)
// MODE 2: dst = lrelu(u3)             (final output)
// ---------------------------------------------------------------------------
template <int MODE>
__global__ __launch_bounds__(256) void rout_layer_k(
    const int* __restrict__ row_ptr, const int* __restrict__ src_sorted,
    const float* __restrict__ xn, float* __restrict__ dst, int n) {
  __shared__ float zc[4][CAP * 64];
  const int wv   = threadIdx.x >> 6;
  const int wid  = blockIdx.x * 4 + wv;
  const int lane = threadIdx.x & 63;
  if (wid >= n) return;
  const int g = lane >> 4;          // edge slot 0..3
  const int q = lane & 15;          // float4 chunk (dims 4q..4q+3)
  const size_t rowj = (size_t)wid * 64 + q * 4;
  float* zbase = &zc[wv][0];

  const float4 xj = *reinterpret_cast<const float4*>(xn + rowj);
  float u0 = xj.x, u1 = xj.y, u2 = xj.z, u3 = xj.w;   // u = x initially

  const int e0  = row_ptr[wid];
  const int end = row_ptr[wid + 1];
  const int ntile = (end - e0 + 3) >> 2;

  for (int t = 0; t < 3; ++t) {
    float a0 = 0.f, a1 = 0.f, a2 = 0.f, a3 = 0.f;

#define EDGE_BODY(Z)                                                   \
    {                                                                  \
      float d = (Z).x * u0;                                            \
      d = fmaf((Z).y, u1, d);                                          \
      d = fmaf((Z).z, u2, d);                                          \
      d = fmaf((Z).w, u3, d);                                          \
      d = dpp_add<0xB1>(d);              /* 8-dim capsule dot */       \
      const float ee = __expf(d);        /* |d|<=1: unit capsules */   \
      float sm = dpp_add<0x4E>(ee);      /* + capsule c^1        */    \
      sm = dpp_add<0x124>(sm);           /* + (c+2,c+3)  ror4    */    \
      sm = dpp_add<0x128>(sm);           /* + remaining 4  ror8  */    \
      const float wgt = ee * __builtin_amdgcn_rcpf(sm);                \
      a0 = fmaf((Z).x, wgt, a0);                                       \
      a1 = fmaf((Z).y, wgt, a1);                                       \
      a2 = fmaf((Z).z, wgt, a2);                                       \
      a3 = fmaf((Z).w, wgt, a3);                                       \
    }

    if (t == 0) {
      int e = e0 + g;
      bool vn = e < end;
      int  sn = vn ? src_sorted[e] : wid;
      float4 zn = *reinterpret_cast<const float4*>(xn + (size_t)sn * 64 + q * 4);
      if (!vn) zn = make_float4(0.f, 0.f, 0.f, 0.f);
      for (int it = 0; it < ntile; ++it) {
        const float4 z = zn;
        e += 4;
        const bool v2 = e < end;
        const int  s2 = v2 ? src_sorted[e] : wid;
        float4 tz = *reinterpret_cast<const float4*>(xn + (size_t)s2 * 64 + q * 4);
        zn = v2 ? tz : make_float4(0.f, 0.f, 0.f, 0.f);
        const int slot = it * 4 + g;
        if (slot < CAP)
          *reinterpret_cast<float4*>(zbase + slot * 64 + q * 4) = z;
        EDGE_BODY(z)
      }
    } else {
      for (int it = 0; it < ntile; ++it) {
        const int slot = it * 4 + g;
        float4 z;
        if (slot < CAP) {
          z = *reinterpret_cast<const float4*>(zbase + slot * 64 + q * 4);
        } else {
          const int e = e0 + slot;
          const bool vv = e < end;
          const int ss = vv ? src_sorted[e] : wid;
          z = *reinterpret_cast<const float4*>(xn + (size_t)ss * 64 + q * 4);
          if (!vv) z = make_float4(0.f, 0.f, 0.f, 0.f);
        }
        EDGE_BODY(z)
      }
    }
#undef EDGE_BODY

    // combine the 4 edge slots (lane bits 4,5)
    a0 += __shfl_xor(a0, 16); a0 += __shfl_xor(a0, 32);
    a1 += __shfl_xor(a1, 16); a1 += __shfl_xor(a1, 32);
    a2 += __shfl_xor(a2, 16); a2 += __shfl_xor(a2, 32);
    a3 += __shfl_xor(a3, 16); a3 += __shfl_xor(a3, 32);
    // + x, capsnorm -> next u
    a0 += xj.x; a1 += xj.y; a2 += xj.z; a3 += xj.w;
    float ss = a0 * a0 + a1 * a1 + a2 * a2 + a3 * a3;
    ss = dpp_add<0xB1>(ss);
    const float inv = 1.0f / fmaxf(sqrtf(ss), EPSN);
    u0 = a0 * inv; u1 = a1 * inv; u2 = a2 * inv; u3 = a3 * inv;
  }

  // boundary transforms
  float v0 = u0, v1 = u1, v2 = u2, v3 = u3;
  v0 = v0 > 0.f ? v0 : SLOPE * v0;
  v1 = v1 > 0.f ? v1 : SLOPE * v1;
  v2 = v2 > 0.f ? v2 : SLOPE * v2;
  v3 = v3 > 0.f ? v3 : SLOPE * v3;
  if (MODE == 1) {   // re-capsnorm for next layer's x
    float s3 = v0 * v0 + v1 * v1 + v2 * v2 + v3 * v3;
    s3 = dpp_add<0xB1>(s3);
    const float inv3 = 1.0f / fmaxf(sqrtf(s3), EPSN);
    v0 *= inv3; v1 *= inv3; v2 *= inv3; v3 *= inv3;
  }
  if (g == 0) {
    *reinterpret_cast<float4*>(dst + rowj) = make_float4(v0, v1, v2, v3);
  }
}

// ---------------------------------------------------------------------------
extern "C" void kernel_launch(void* const* d_in, const int* in_sizes, int n_in,
                              void* d_out, int out_size, void* d_ws, size_t ws_size,
                              hipStream_t stream) {
  const float* x       = (const float*)d_in[0];
  const int*   src_trg = (const int*)d_in[1];
  const float* W       = (const float*)d_in[2];
  const float* b       = (const float*)d_in[3];

  const int hid    = in_sizes[3];          // 64
  const int in_dim = in_sizes[2] / hid;    // 500
  const int n      = in_sizes[0] / in_dim; // 50000
  const int m      = in_sizes[1] / 2;      // 500000
  const int* src = src_trg;
  const int* trg = src_trg + m;

  const size_t n64 = (size_t)n * hid;      // 3.2M floats
  float* xn_a = (float*)d_ws;              // layer-1 normalized features
  float* xn_b = xn_a + n64;                // layer-2 normalized features
  short* w2h  = (short*)(xn_b + n64);      // KPAD*64 bf16 hi (swizzled)
  short* w2l  = w2h + KPAD * 64;           // KPAD*64 bf16 lo
  int*   ip   = (int*)(w2l + KPAD * 64);
  int* counts     = ip;                    // n
  int* row_ptr    = counts + n;            // n+1
  int* cursor     = row_ptr + n + 1;       // n
  int* bsum       = cursor + n;            // nblk
  const int nblk  = (n + 255) / 256;       // 196 (<= 256 required by scanB)
  int* src_sorted = bsum + nblk;           // m
  float* out = (float*)d_out;

  const int mg = (m + 255) / 256;

  // --- CSR build (once per call) ---
  zero_int_k<<<nblk, 256, 0, stream>>>(counts, n);
  hist_k<<<mg, 256, 0, stream>>>(trg, counts, m);
  scanA_k<<<nblk, 256, 0, stream>>>(counts, bsum, n);
  scanB_k<<<1, 256, 0, stream>>>(bsum, nblk, row_ptr, n, m);
  scanC_k<<<nblk, 256, 0, stream>>>(counts, bsum, row_ptr, cursor, n);
  scatter_k<<<mg, 256, 0, stream>>>(src, trg, cursor, src_sorted, m);

  // --- W prep + fused MFMA GEMM: xn_a = capsnorm(lrelu(x @ W + b)) ---
  prep_w_k<<<(KPAD * 64) / 256, 256, 0, stream>>>(W, w2h, w2l, in_dim);
  gemm_mfma_capsnorm_k<<<(n + 63) / 64, 256, 0, stream>>>(
      x, w2h, w2l, b, xn_a, n, in_dim);

  // --- routing: one fused kernel per layer (3 iterations each) ---
  const int rb = (n + 3) / 4;  // 4 waves (nodes) per 256-thread block
  rout_layer_k<1><<<rb, 256, 0, stream>>>(row_ptr, src_sorted, xn_a, xn_b, n);
  rout_layer_k<2><<<rb, 256, 0, stream>>>(row_ptr, src_sorted, xn_b, out, n);
}